// Round 7
// baseline (826.673 us; speedup 1.0000x reference)
//
#include <hip/hip_runtime.h>
#include <math.h>

#define EPSV 1e-5f
#define HD 128
#define IT 128
#define JT 32
#define WP 132
#define CCH 16
#define THR 256

typedef __attribute__((address_space(3))) uint32_t lds_u32_t;
typedef __attribute__((address_space(1))) uint32_t gbl_u32_t;

__device__ __forceinline__ void async_copy16(const float* g, float* l) {
    __builtin_amdgcn_global_load_lds((const gbl_u32_t*)g, (lds_u32_t*)l, 16, 0, 0);
}

// stage a JT x HD fp32 tile (16 KB) global -> LDS via async DMA (256 threads)
__device__ __forceinline__ void stage_tile_async(const float* gsrc, float* lds, int t) {
    int wv = t >> 6, lane = t & 63;
#pragma unroll
    for (int it = 0; it < 4; ++it) {
        int c = it * 4 + wv;
        async_copy16(gsrc + c * 256 + lane * 4, lds + c * 256);
    }
}

// ---------------- normalization scale kernels ----------------

__global__ void colsum_part_k(const float* __restrict__ A, float* __restrict__ s1p,
                              int B, int NO, int NV) {
    int v = blockIdx.x * 256 + threadIdx.x;
    int c = blockIdx.y, b = blockIdx.z;
    if (v >= NV) return;
    int chunk = (NO + CCH - 1) / CCH;
    int o0 = c * chunk;
    int o1 = o0 + chunk; if (o1 > NO) o1 = NO;
    const float* Ab = A + (size_t)b * NO * NV + v;
    float s = 0.f;
    for (int o = o0; o < o1; ++o) s += Ab[(size_t)o * NV];
    s1p[((size_t)b * CCH + c) * NV + v] = s;
}

__global__ void colsum_fin_k(const float* __restrict__ s1p, float* __restrict__ rs1,
                             int B, int NV) {
    int idx = blockIdx.x * 256 + threadIdx.x;
    if (idx >= B * NV) return;
    int b = idx / NV, v = idx - b * NV;
    float s = 0.f;
    for (int c = 0; c < CCH; ++c) s += s1p[((size_t)b * CCH + c) * NV + v];
    rs1[idx] = 1.f / (s + EPSV);
}

__global__ void rowsum_inv_k(const float* __restrict__ A, const float* __restrict__ rs1,
                             float* __restrict__ rs2, int B, int NO, int NV) {
    int row = blockIdx.x * (blockDim.x >> 6) + (threadIdx.x >> 6);
    int lane = threadIdx.x & 63;
    if (row >= B * NO) return;
    int b = row / NO;
    const float* Ar = A + (size_t)row * NV;
    const float* r1 = rs1 + (size_t)b * NV;
    float s = 0.f;
    for (int v = lane; v < NV; v += 64) s += Ar[v] * r1[v];
    for (int off = 32; off; off >>= 1) s += __shfl_xor(s, off, 64);
    if (lane == 0) rs2[row] = 1.f / (s + EPSV);
}

// ---------------- GAT h-GEMM + fused score vectors ----------------
__global__ __launch_bounds__(128)
void gath_k(const float* __restrict__ X, const float* __restrict__ W,
            const float* __restrict__ a1, const float* __restrict__ a2,
            float* __restrict__ h, float* __restrict__ sa, float* __restrict__ sb,
            int rows, int K) {
    extern __shared__ float xs[];
    int row0 = blockIdx.x * 8;
    int t = threadIdx.x;
    int K4 = K >> 2;
    for (int l = t; l < 8 * K4; l += 128) {
        int r = l / K4, c4 = l - r * K4;
        int row = row0 + r;
        float4 v = make_float4(0.f, 0.f, 0.f, 0.f);
        if (row < rows) v = ((const float4*)(X + (size_t)row * K))[c4];
        ((float4*)&xs[(size_t)r * K])[c4] = v;
    }
    __syncthreads();
    int wv = t >> 6, tt = t & 63, rb = wv * 4;
    float a0[4] = {0.f, 0.f, 0.f, 0.f}, a1v[4] = {0.f, 0.f, 0.f, 0.f};
#pragma unroll 4
    for (int k = 0; k < K; ++k) {
        float w0 = W[(size_t)k * HD + tt];
        float w1 = W[(size_t)k * HD + tt + 64];
#pragma unroll
        for (int r = 0; r < 4; ++r) {
            float x = xs[(size_t)(rb + r) * K + k];
            a0[r] = fmaf(x, w0, a0[r]);
            a1v[r] = fmaf(x, w1, a1v[r]);
        }
    }
    float A1 = a1[tt], A1b = a1[tt + 64], A2 = a2[tt], A2b = a2[tt + 64];
#pragma unroll
    for (int r = 0; r < 4; ++r) {
        int row = row0 + rb + r;
        if (row < rows) {
            h[(size_t)row * HD + tt]      = a0[r];
            h[(size_t)row * HD + tt + 64] = a1v[r];
        }
        float p = a0[r] * A1 + a1v[r] * A1b;
        float q = a0[r] * A2 + a1v[r] * A2b;
#pragma unroll
        for (int off = 32; off; off >>= 1) {
            p += __shfl_xor(p, off, 64);
            q += __shfl_xor(q, off, 64);
        }
        if (tt == 0 && row < rows) { sa[row] = p; sb[row] = q; }
    }
}

__global__ __launch_bounds__(256)
void sbmax_k(const float* __restrict__ sb, float* __restrict__ sbmax, int N) {
    __shared__ float red[256];
    int b = blockIdx.x, t = threadIdx.x;
    float m = -INFINITY;
    for (int j = t; j < N; j += 256) m = fmaxf(m, sb[(size_t)b * N + j]);
    red[t] = m; __syncthreads();
    for (int s = 128; s; s >>= 1) {
        if (t < s) red[t] = fmaxf(red[t], red[t + s]);
        __syncthreads();
    }
    if (t == 0) sbmax[b] = red[0];
}

// ---------------- 256-thread tile FMA: 8 rows x 8 channels per thread ----------------
// thread rg = t>>4 owns rows rg*8..rg*8+7 ; c0 = (t&15)*4 owns ch c0..c0+3, c0+64..+67
__device__ __forceinline__ void tile_fma256(const float (*hs)[HD], const float (*ws)[WP],
                                            int rg, int c0, float acc[8][8]) {
#pragma unroll 4
    for (int jl = 0; jl < JT; ++jl) {
        float4 h0 = *(const float4*)&hs[jl][c0];
        float4 h1 = *(const float4*)&hs[jl][c0 + 64];
        float4 w0 = *(const float4*)&ws[jl][rg * 8];
        float4 w1 = *(const float4*)&ws[jl][rg * 8 + 4];
        float wq[8] = {w0.x, w0.y, w0.z, w0.w, w1.x, w1.y, w1.z, w1.w};
#pragma unroll
        for (int q = 0; q < 8; ++q) {
            float w = wq[q];
            acc[q][0] = fmaf(w, h0.x, acc[q][0]);
            acc[q][1] = fmaf(w, h0.y, acc[q][1]);
            acc[q][2] = fmaf(w, h0.z, acc[q][2]);
            acc[q][3] = fmaf(w, h0.w, acc[q][3]);
            acc[q][4] = fmaf(w, h1.x, acc[q][4]);
            acc[q][5] = fmaf(w, h1.y, acc[q][5]);
            acc[q][6] = fmaf(w, h1.z, acc[q][6]);
            acc[q][7] = fmaf(w, h1.w, acc[q][7]);
        }
    }
}

__device__ __forceinline__ void part_store256(float* __restrict__ pp, size_t base,
                                              int i0, int N, int rg, int c0,
                                              float acc[8][8]) {
#pragma unroll
    for (int q = 0; q < 8; ++q) {
        int i = i0 + rg * 8 + q;
        if (i >= N) continue;
        float* op = pp + base + (size_t)i * HD;
        *(float4*)&op[c0]      = make_float4(acc[q][0], acc[q][1], acc[q][2], acc[q][3]);
        *(float4*)&op[c0 + 64] = make_float4(acc[q][4], acc[q][5], acc[q][6], acc[q][7]);
    }
}

// ---------------- GAT aggregation: pipelined, 1 barrier/tile, IT=128 ----------------
__global__ __launch_bounds__(256)
void gat_agg_k(const float* __restrict__ adj, const float* __restrict__ h,
               const float* __restrict__ sa, const float* __restrict__ sb,
               const float* __restrict__ sbmax, float* __restrict__ ppart,
               float* __restrict__ zpart, int B, int N, int tilesPerSplit) {
    __shared__ float hs[2][JT][HD];
    __shared__ float ws[2][JT][WP];
    __shared__ float sa_s[IT], m_s[IT];
    int tilesPerB = (N + IT - 1) / IT;
    int b = blockIdx.x / tilesPerB;
    int i0 = (blockIdx.x - b * tilesPerB) * IT;
    int split = blockIdx.y;
    int j_begin = split * tilesPerSplit * JT;
    if (j_begin >= N) return;
    int j_end = j_begin + tilesPerSplit * JT;
    if (j_end > N) j_end = N;
    int T = (j_end - j_begin + JT - 1) / JT;
    int t = threadIdx.x;
    if (t < IT) {
        int i = i0 + t;
        float s = (i < N) ? sa[(size_t)b * N + i] : 0.f;
        sa_s[t] = s;
        float e = s + sbmax[b];
        m_s[t] = e > 0.f ? e : 0.2f * e;
    }
    __syncthreads();   // sa_s/m_s visible to ALL waves before first ws computation
    int rg = t >> 4, c0 = (t & 15) * 4;
    int il = t >> 1, jh = (t & 1) * 16;     // adj: thread owns row il, 16 j values
    float acc[8][8];
#pragma unroll
    for (int q = 0; q < 8; ++q)
#pragma unroll
        for (int x = 0; x < 8; ++x) acc[q][x] = 0.f;
    float zacc = 0.f;
    const float* adjb = adj + ((size_t)b * N + i0) * N;
    const float* hb = h + (size_t)b * N * HD;
    const float* sbb = sb + (size_t)b * N;
    int irow = i0 + il;
    // prologue: DMA tile0 + adj/sb regs tile0
    stage_tile_async(hb + (size_t)j_begin * HD, &hs[0][0][0], t);
    float4 a4[4], s4[4];
#pragma unroll
    for (int k = 0; k < 4; ++k) {
        int j = j_begin + jh + k * 4;
        float4 av = make_float4(0.f,0.f,0.f,0.f), sv = make_float4(0.f,0.f,0.f,0.f);
        if (irow < N) {
            if (j + 3 < N) {
                av = *(const float4*)&adjb[(size_t)il * N + j];
                sv = *(const float4*)&sbb[j];
            } else {
                float* ap = (float*)&av; float* sp = (float*)&sv;
                for (int r = 0; r < 4; ++r)
                    if (j + r < N) { ap[r] = adjb[(size_t)il * N + j + r]; sp[r] = sbb[j + r]; }
            }
        }
        a4[k] = av; s4[k] = sv;
    }
    for (int tt = 0; tt < T; ++tt) {
        int cur = tt & 1;
        float sai = sa_s[il], m = m_s[il];
#pragma unroll
        for (int k = 0; k < 4; ++k) {
            float av[4] = {a4[k].x, a4[k].y, a4[k].z, a4[k].w};
            float sv[4] = {s4[k].x, s4[k].y, s4[k].z, s4[k].w};
#pragma unroll
            for (int r = 0; r < 4; ++r) {
                float e = sai + sv[r];
                e = e > 0.f ? e : 0.2f * e;
                ws[cur][jh + k * 4 + r][il] = av[r] > 0.f ? __expf(e - m) : 0.f;
            }
        }
        __syncthreads();   // ws[cur] visible; hs[cur] DMA drained
        if (tt + 1 < T) {
            int jn = j_begin + (tt + 1) * JT;
            stage_tile_async(hb + (size_t)jn * HD, &hs[1 - cur][0][0], t);
#pragma unroll
            for (int k = 0; k < 4; ++k) {
                int j = jn + jh + k * 4;
                float4 av = make_float4(0.f,0.f,0.f,0.f), sv = make_float4(0.f,0.f,0.f,0.f);
                if (irow < N) {
                    if (j + 3 < N) {
                        av = *(const float4*)&adjb[(size_t)il * N + j];
                        sv = *(const float4*)&sbb[j];
                    } else {
                        float* ap = (float*)&av; float* sp = (float*)&sv;
                        for (int r = 0; r < 4; ++r)
                            if (j + r < N) { ap[r] = adjb[(size_t)il * N + j + r]; sp[r] = sbb[j + r]; }
                    }
                }
                a4[k] = av; s4[k] = sv;
            }
        }
        tile_fma256(hs[cur], ws[cur], rg, c0, acc);
        if (t < IT) {
            float z = 0.f;
#pragma unroll 8
            for (int jl = 0; jl < JT; ++jl) z += ws[cur][jl][t];
            zacc += z;
        }
    }
    size_t rowsTot = (size_t)B * N;
    part_store256(ppart, ((size_t)split * rowsTot + (size_t)b * N) * HD, i0, N, rg, c0, acc);
    if (t < IT && i0 + t < N)
        zpart[(size_t)split * rowsTot + (size_t)b * N + i0 + t] = zacc;
}

// ---------------- cross vo: pipelined (out rows = NV, j over NO) ----------------
__global__ __launch_bounds__(256)
void cross_vo_k(const float* __restrict__ A, const float* __restrict__ src,
                float* __restrict__ ppart, int B, int NO, int NV, int tilesPerSplit) {
    __shared__ float hs[2][JT][HD];
    __shared__ float ws[2][JT][WP];
    int tilesPerB = (NV + IT - 1) / IT;
    int b = blockIdx.x / tilesPerB;
    int i0 = (blockIdx.x - b * tilesPerB) * IT;
    int split = blockIdx.y;
    int j_begin = split * tilesPerSplit * JT;
    if (j_begin >= NO) return;
    int j_end = j_begin + tilesPerSplit * JT;
    if (j_end > NO) j_end = NO;
    int T = (j_end - j_begin + JT - 1) / JT;
    int t = threadIdx.x;
    int rg = t >> 4, c0 = (t & 15) * 4;
    int il = t & 127, jlb = t >> 7;         // column v = i0+il, o rows jlb + 2k
    float acc[8][8];
#pragma unroll
    for (int q = 0; q < 8; ++q)
#pragma unroll
        for (int x = 0; x < 8; ++x) acc[q][x] = 0.f;
    const float* Ab = A + (size_t)b * NO * NV;
    const float* srcb = src + (size_t)b * NO * HD;
    int v = i0 + il;
    float w16[16];
    stage_tile_async(srcb + (size_t)j_begin * HD, &hs[0][0][0], t);
#pragma unroll
    for (int k = 0; k < 16; ++k) {
        int o = j_begin + jlb + k * 2;
        w16[k] = (v < NV && o < NO) ? Ab[(size_t)o * NV + v] : 0.f;
    }
    for (int tt = 0; tt < T; ++tt) {
        int cur = tt & 1;
#pragma unroll
        for (int k = 0; k < 16; ++k) ws[cur][jlb + k * 2][il] = w16[k];
        __syncthreads();
        if (tt + 1 < T) {
            int jn = j_begin + (tt + 1) * JT;
            stage_tile_async(srcb + (size_t)jn * HD, &hs[1 - cur][0][0], t);
#pragma unroll
            for (int k = 0; k < 16; ++k) {
                int o = jn + jlb + k * 2;
                w16[k] = (v < NV && o < NO) ? Ab[(size_t)o * NV + v] : 0.f;
            }
        }
        tile_fma256(hs[cur], ws[cur], rg, c0, acc);
    }
    size_t rowsTot = (size_t)B * NV;
    part_store256(ppart, ((size_t)split * rowsTot + (size_t)b * NV) * HD, i0, NV, rg, c0, acc);
}

// ---------------- cross ov: pipelined (out rows = NO, j over NV; rs1 folded) --------
__global__ __launch_bounds__(256)
void cross_ov_k(const float* __restrict__ A, const float* __restrict__ src,
                const float* __restrict__ rs1, float* __restrict__ ppart,
                int B, int NO, int NV, int tilesPerSplit) {
    __shared__ float hs[2][JT][HD];
    __shared__ float ws[2][JT][WP];
    int tilesPerB = (NO + IT - 1) / IT;
    int b = blockIdx.x / tilesPerB;
    int i0 = (blockIdx.x - b * tilesPerB) * IT;
    int split = blockIdx.y;
    int j_begin = split * tilesPerSplit * JT;
    if (j_begin >= NV) return;
    int j_end = j_begin + tilesPerSplit * JT;
    if (j_end > NV) j_end = NV;
    int T = (j_end - j_begin + JT - 1) / JT;
    int t = threadIdx.x;
    int rg = t >> 4, c0 = (t & 15) * 4;
    int il = t >> 1, vh = (t & 1) * 16;
    float acc[8][8];
#pragma unroll
    for (int q = 0; q < 8; ++q)
#pragma unroll
        for (int x = 0; x < 8; ++x) acc[q][x] = 0.f;
    const float* Ab = A + (size_t)b * NO * NV;
    const float* srcb = src + (size_t)b * NV * HD;
    const float* r1b = rs1 + (size_t)b * NV;
    int orow = i0 + il;
    float4 a4[4], r4[4];
    stage_tile_async(srcb + (size_t)j_begin * HD, &hs[0][0][0], t);
#pragma unroll
    for (int k = 0; k < 4; ++k) {
        int vv = j_begin + vh + k * 4;
        float4 av = make_float4(0.f,0.f,0.f,0.f), rv = make_float4(0.f,0.f,0.f,0.f);
        if (orow < NO) {
            if (vv + 3 < NV) {
                av = *(const float4*)&Ab[(size_t)orow * NV + vv];
                rv = *(const float4*)&r1b[vv];
            } else {
                float* ap = (float*)&av; float* rp = (float*)&rv;
                for (int r = 0; r < 4; ++r)
                    if (vv + r < NV) { ap[r] = Ab[(size_t)orow * NV + vv + r]; rp[r] = r1b[vv + r]; }
            }
        }
        a4[k] = av; r4[k] = rv;
    }
    for (int tt = 0; tt < T; ++tt) {
        int cur = tt & 1;
#pragma unroll
        for (int k = 0; k < 4; ++k) {
            float wv[4] = {a4[k].x * r4[k].x, a4[k].y * r4[k].y,
                           a4[k].z * r4[k].z, a4[k].w * r4[k].w};
#pragma unroll
            for (int r = 0; r < 4; ++r) ws[cur][vh + k * 4 + r][il] = wv[r];
        }
        __syncthreads();
        if (tt + 1 < T) {
            int jn = j_begin + (tt + 1) * JT;
            stage_tile_async(srcb + (size_t)jn * HD, &hs[1 - cur][0][0], t);
#pragma unroll
            for (int k = 0; k < 4; ++k) {
                int vv = jn + vh + k * 4;
                float4 av = make_float4(0.f,0.f,0.f,0.f), rv = make_float4(0.f,0.f,0.f,0.f);
                if (orow < NO) {
                    if (vv + 3 < NV) {
                        av = *(const float4*)&Ab[(size_t)orow * NV + vv];
                        rv = *(const float4*)&r1b[vv];
                    } else {
                        float* ap = (float*)&av; float* rp = (float*)&rv;
                        for (int r = 0; r < 4; ++r)
                            if (vv + r < NV) { ap[r] = Ab[(size_t)orow * NV + vv + r]; rp[r] = r1b[vv + r]; }
                    }
                }
                a4[k] = av; r4[k] = rv;
            }
        }
        tile_fma256(hs[cur], ws[cur], rg, c0, acc);
    }
    size_t rowsTot = (size_t)B * NO;
    part_store256(ppart, ((size_t)split * rowsTot + (size_t)b * NO) * HD, i0, NO, rg, c0, acc);
}

// ---------------- finalize GAT: sum S partials, /Z, relu ----------------
__global__ __launch_bounds__(256)
void finalize_gat_k(const float* __restrict__ pp, const float* __restrict__ zp,
                    float* __restrict__ out, int rows, int S) {
    int idx = blockIdx.x * 256 + threadIdx.x;
    int total = rows * (HD / 4);
    if (idx >= total) return;
    int row = idx >> 5;
    float4 v = make_float4(0.f, 0.f, 0.f, 0.f);
    for (int s = 0; s < S; ++s) {
        float4 p = ((const float4*)pp)[((size_t)s * rows + row) * (HD / 4) + (idx & 31)];
        v.x += p.x; v.y += p.y; v.z += p.z; v.w += p.w;
    }
    float z = 0.f;
    for (int s = 0; s < S; ++s) z += zp[(size_t)s * rows + row];
    float sc = 1.f / z;
    v.x = fmaxf(v.x * sc, 0.f); v.y = fmaxf(v.y * sc, 0.f);
    v.z = fmaxf(v.z * sc, 0.f); v.w = fmaxf(v.w * sc, 0.f);
    ((float4*)out)[idx] = v;
}

// ---------------- fused MLP: out = (relu(x@W1+b1))@W2 + b2 + res ----------------
__global__ __launch_bounds__(128)
void mlp_k(const float* __restrict__ pp, const float* __restrict__ scale, int S,
           const float* __restrict__ W1, const float* __restrict__ b1,
           const float* __restrict__ W2, const float* __restrict__ b2,
           const float* __restrict__ res, float* __restrict__ out, int rows) {
    __shared__ float xs[8][HD];
    __shared__ float hh[8][HD];
    int row0 = blockIdx.x * 8;
    int t = threadIdx.x;
    for (int l = t; l < 8 * 32; l += 128) {
        int r = l >> 5, c4 = l & 31;
        int row = row0 + r;
        float4 v = make_float4(0.f, 0.f, 0.f, 0.f);
        if (row < rows) {
            for (int s = 0; s < S; ++s) {
                float4 p = ((const float4*)pp)[((size_t)s * rows + row) * 32 + c4];
                v.x += p.x; v.y += p.y; v.z += p.z; v.w += p.w;
            }
            float sc = scale[row];
            v.x *= sc; v.y *= sc; v.z *= sc; v.w *= sc;
        }
        ((float4*)&xs[r][0])[c4] = v;
    }
    __syncthreads();
    int wv = t >> 6, tt = t & 63, rb = wv * 4;
    float a0[4] = {0.f, 0.f, 0.f, 0.f}, a1v[4] = {0.f, 0.f, 0.f, 0.f};
#pragma unroll 4
    for (int k = 0; k < HD; ++k) {
        float w0 = W1[(size_t)k * HD + tt];
        float w1 = W1[(size_t)k * HD + tt + 64];
#pragma unroll
        for (int r = 0; r < 4; ++r) {
            float x = xs[rb + r][k];
            a0[r] = fmaf(x, w0, a0[r]);
            a1v[r] = fmaf(x, w1, a1v[r]);
        }
    }
    float bb0 = b1[tt], bb1 = b1[tt + 64];
#pragma unroll
    for (int r = 0; r < 4; ++r) {
        hh[rb + r][tt]      = fmaxf(a0[r] + bb0, 0.f);
        hh[rb + r][tt + 64] = fmaxf(a1v[r] + bb1, 0.f);
    }
    __syncthreads();
    float c0a[4] = {0.f, 0.f, 0.f, 0.f}, c1a[4] = {0.f, 0.f, 0.f, 0.f};
#pragma unroll 4
    for (int k = 0; k < HD; ++k) {
        float w0 = W2[(size_t)k * HD + tt];
        float w1 = W2[(size_t)k * HD + tt + 64];
#pragma unroll
        for (int r = 0; r < 4; ++r) {
            float x = hh[rb + r][k];
            c0a[r] = fmaf(x, w0, c0a[r]);
            c1a[r] = fmaf(x, w1, c1a[r]);
        }
    }
    float d0 = b2[tt], d1 = b2[tt + 64];
#pragma unroll
    for (int r = 0; r < 4; ++r) {
        int row = row0 + rb + r;
        if (row >= rows) continue;
        out[(size_t)row * HD + tt]      = c0a[r] + d0 + res[(size_t)row * HD + tt];
        out[(size_t)row * HD + tt + 64] = c1a[r] + d1 + res[(size_t)row * HD + tt + 64];
    }
}

// ---------------- output projection ----------------
template<int RELU, int BIAS, int RES>
__global__ __launch_bounds__(128)
void linear_k(const float* __restrict__ X, const float* __restrict__ W,
              const float* __restrict__ bias, const float* __restrict__ res,
              float* __restrict__ out, int rows, int K, int Dout) {
    __shared__ float xs[4][512];
    int row0 = blockIdx.x * 4;
    int t = threadIdx.x;
    int K4 = K >> 2;
    for (int l = t; l < 4 * K4; l += 128) {
        int r = l / K4, c4 = l - r * K4;
        float4 val = make_float4(0.f, 0.f, 0.f, 0.f);
        if (row0 + r < rows) val = ((const float4*)(X + (size_t)(row0 + r) * K))[c4];
        ((float4*)&xs[r][0])[c4] = val;
    }
    __syncthreads();
    int chunk = Dout < 256 ? Dout : 256;
    int half = chunk >> 1;
    if (t >= half) return;
    int c0 = blockIdx.y * chunk + t;
    int c1 = c0 + half;
    float a00 = 0, a01 = 0, a02 = 0, a03 = 0, a10 = 0, a11 = 0, a12 = 0, a13 = 0;
#pragma unroll 4
    for (int k = 0; k < K; ++k) {
        float w0 = W[(size_t)k * Dout + c0];
        float w1 = W[(size_t)k * Dout + c1];
        float x0 = xs[0][k], x1 = xs[1][k], x2 = xs[2][k], x3 = xs[3][k];
        a00 = fmaf(x0, w0, a00); a01 = fmaf(x1, w0, a01);
        a02 = fmaf(x2, w0, a02); a03 = fmaf(x3, w0, a03);
        a10 = fmaf(x0, w1, a10); a11 = fmaf(x1, w1, a11);
        a12 = fmaf(x2, w1, a12); a13 = fmaf(x3, w1, a13);
    }
    float accs[2][4] = {{a00, a01, a02, a03}, {a10, a11, a12, a13}};
    int cs[2] = {c0, c1};
    for (int h = 0; h < 2; ++h) {
        float bv = BIAS ? bias[cs[h]] : 0.f;
        for (int r = 0; r < 4; ++r) {
            int row = row0 + r;
            if (row >= rows) continue;
            float v = accs[h][r] + bv;
            if (RES) v += res[(size_t)row * Dout + cs[h]];
            if (RELU) v = fmaxf(v, 0.f);
            out[(size_t)row * Dout + cs[h]] = v;
        }
    }
}

// ---------------- host launcher ----------------
extern "C" void kernel_launch(void* const* d_in, const int* in_sizes, int n_in,
                              void* d_out, int out_size, void* d_ws, size_t ws_size,
                              hipStream_t stream) {
    const int B = 8, NV = 500, NO = 1500, DV = 512, DO = 32;
    const float* vis_memory = (const float*)d_in[0];
    const float* obj_memory = (const float*)d_in[1];
    const float* vis_adj    = (const float*)d_in[2];
    const float* obj_adj    = (const float*)d_in[3];
    const float* A_OV       = (const float*)d_in[4];
    const float* Wv1  = (const float*)d_in[5];
    const float* av1a = (const float*)d_in[6];
    const float* av1b = (const float*)d_in[7];
    const float* Wv2  = (const float*)d_in[8];
    const float* av2a = (const float*)d_in[9];
    const float* av2b = (const float*)d_in[10];
    const float* Wo1  = (const float*)d_in[11];
    const float* ao1a = (const float*)d_in[12];
    const float* ao1b = (const float*)d_in[13];
    const float* Wo2  = (const float*)d_in[14];
    const float* ao2a = (const float*)d_in[15];
    const float* ao2b = (const float*)d_in[16];
    const float* g2o_W1 = (const float*)d_in[17];
    const float* g2o_b1 = (const float*)d_in[18];
    const float* g2o_W2 = (const float*)d_in[19];
    const float* g2o_b2 = (const float*)d_in[20];
    const float* o2g_W1 = (const float*)d_in[21];
    const float* o2g_b1 = (const float*)d_in[22];
    const float* o2g_W2 = (const float*)d_in[23];
    const float* o2g_b2 = (const float*)d_in[24];
    const float* img_W = (const float*)d_in[25];
    const float* img_b = (const float*)d_in[26];
    const float* obj_W = (const float*)d_in[27];
    const float* obj_b = (const float*)d_in[28];

    float* wsp = (float*)d_ws;
    size_t off = 0;
    auto alloc = [&](size_t n) { float* p = wsp + off; off += n; return p; };
    float* rs1   = alloc(B * NV);
    float* rs2   = alloc(B * NO);
    float* sa    = alloc(B * NO);
    float* sbv   = alloc(B * NO);
    float* sbmax = alloc(B);
    float* s1p   = alloc((size_t)B * CCH * NV);
    float* hv    = alloc((size_t)B * NV * HD);
    float* ho    = alloc((size_t)B * NO * HD);
    float* v1    = alloc((size_t)B * NV * HD);
    float* o1    = alloc((size_t)B * NO * HD);
    float* visb  = alloc((size_t)B * NV * HD);
    float* objb  = alloc((size_t)B * NO * HD);
    float* ppart = alloc((size_t)8 * B * NO * HD);
    float* zpart = alloc((size_t)8 * B * NO);
    alloc(16384);                                    // tail pad for async OOB reads

    colsum_part_k<<<dim3((NV + 255) / 256, CCH, B), 256, 0, stream>>>(A_OV, s1p, B, NO, NV);
    colsum_fin_k<<<dim3((B * NV + 255) / 256), 256, 0, stream>>>(s1p, rs1, B, NV);
    rowsum_inv_k<<<dim3((B * NO + 3) / 4), 256, 0, stream>>>(A_OV, rs1, rs2, B, NO, NV);

    const int vtiles = (NV + IT - 1) / IT;   // 4
    const int otiles = (NO + IT - 1) / IT;   // 12
    const int S_GAT_O = 5, S_GAT_V = 8, S_VO = 16, S_OV = 4;
    auto tps = [](int n, int S) { int tj = (n + JT - 1) / JT; return (tj + S - 1) / S; };

    auto gat = [&](const float* X, int N, int K, const float* W, const float* a1,
                   const float* a2, const float* adj, float* hbuf, float* outbuf) {
        gath_k<<<dim3(B * N / 8), 128, 8 * K * 4, stream>>>(X, W, a1, a2, hbuf, sa, sbv, B * N, K);
        sbmax_k<<<dim3(B), 256, 0, stream>>>(sbv, sbmax, N);
        int tiles = (N + IT - 1) / IT;
        int S = (N == NO) ? S_GAT_O : S_GAT_V;
        gat_agg_k<<<dim3(B * tiles, S), THR, 0, stream>>>(
            adj, hbuf, sa, sbv, sbmax, ppart, zpart, B, N, tps(N, S));
        finalize_gat_k<<<dim3((B * N * (HD / 4) + 255) / 256), 256, 0, stream>>>(
            ppart, zpart, outbuf, B * N, S);
    };

    auto cross_and_mlp = [&](const float* vsrc, const float* osrc, float* visout, float* objout) {
        cross_vo_k<<<dim3(B * vtiles, S_VO), THR, 0, stream>>>(
            A_OV, osrc, ppart, B, NO, NV, tps(NO, S_VO));
        mlp_k<<<dim3(B * NV / 8), 128, 0, stream>>>(
            ppart, rs1, S_VO, o2g_W1, o2g_b1, o2g_W2, o2g_b2, vsrc, visout, B * NV);
        cross_ov_k<<<dim3(B * otiles, S_OV), THR, 0, stream>>>(
            A_OV, vsrc, rs1, ppart, B, NO, NV, tps(NV, S_OV));
        mlp_k<<<dim3(B * NO / 8), 128, 0, stream>>>(
            ppart, rs2, S_OV, g2o_W1, g2o_b1, g2o_W2, g2o_b2, osrc, objout, B * NO);
    };

    // layer 1
    gat(vis_memory, NV, DV, Wv1, av1a, av1b, vis_adj, hv, v1);
    gat(obj_memory, NO, DO, Wo1, ao1a, ao1b, obj_adj, ho, o1);
    cross_and_mlp(v1, o1, visb, objb);

    // layer 2
    gat(visb, NV, HD, Wv2, av2a, av2b, vis_adj, hv, v1);
    gat(objb, NO, HD, Wo2, ao2a, ao2b, obj_adj, ho, o1);
    cross_and_mlp(v1, o1, visb, objb);

    // output projections
    float* vis_out = (float*)d_out;
    float* obj_out = vis_out + (size_t)B * NV * DV;
    linear_k<0, 1, 0><<<dim3((B * NV + 3) / 4, (DV + 255) / 256), 128, 0, stream>>>(
        visb, img_W, img_b, nullptr, vis_out, B * NV, HD, DV);
    linear_k<0, 1, 0><<<dim3((B * NO + 3) / 4, 1), 128, 0, stream>>>(
        objb, obj_W, obj_b, nullptr, obj_out, B * NO, HD, DO);
}

// Round 8
// 710.617 us; speedup vs baseline: 1.1633x; 1.1633x over previous
//
#include <hip/hip_runtime.h>
#include <math.h>

#define EPSV 1e-5f
#define HD 128
#define IT 64
#define JT 32
#define WP 68
#define CCH 16
#define THR 256

typedef __attribute__((address_space(3))) uint32_t lds_u32_t;
typedef __attribute__((address_space(1))) uint32_t gbl_u32_t;

__device__ __forceinline__ void async_copy16(const float* g, float* l) {
    __builtin_amdgcn_global_load_lds((const gbl_u32_t*)g, (lds_u32_t*)l, 16, 0, 0);
}

// stage a JT x HD fp32 tile (16 KB) global -> LDS via async DMA (256 threads)
__device__ __forceinline__ void stage_tile_async(const float* gsrc, float* lds, int t) {
    int wv = t >> 6, lane = t & 63;
#pragma unroll
    for (int it = 0; it < 4; ++it) {
        int c = it * 4 + wv;
        async_copy16(gsrc + c * 256 + lane * 4, lds + c * 256);
    }
}

// ---------------- param structs for fused (vis+obj) launches ----------------
struct GathP { const float *X, *W, *a1, *a2; float *h, *sa, *sb; int rows, K; };
struct AggP  { const float *adj, *h, *sa, *sb, *sm; float *pp, *zp; int N, tiles, tps; };
struct CrossP{ const float *A, *src, *rs1; float *pp; int iN, jN, tiles, tps; };
struct FinP  { const float *pp, *zp; float *out; int rows, S; };
struct MlpP  { const float *pp, *scale; int S; const float *W1, *b1, *W2, *b2, *res;
               float *out; int rows; };

// ---------------- normalization scale kernels ----------------

__global__ void colsum_part_k(const float* __restrict__ A, float* __restrict__ s1p,
                              int B, int NO, int NV) {
    int v = blockIdx.x * 256 + threadIdx.x;
    int c = blockIdx.y, b = blockIdx.z;
    if (v >= NV) return;
    int chunk = (NO + CCH - 1) / CCH;
    int o0 = c * chunk;
    int o1 = o0 + chunk; if (o1 > NO) o1 = NO;
    const float* Ab = A + (size_t)b * NO * NV + v;
    float s = 0.f;
    for (int o = o0; o < o1; ++o) s += Ab[(size_t)o * NV];
    s1p[((size_t)b * CCH + c) * NV + v] = s;
}

__global__ void colsum_fin_k(const float* __restrict__ s1p, float* __restrict__ rs1,
                             int B, int NV) {
    int idx = blockIdx.x * 256 + threadIdx.x;
    if (idx >= B * NV) return;
    int b = idx / NV, v = idx - b * NV;
    float s = 0.f;
    for (int c = 0; c < CCH; ++c) s += s1p[((size_t)b * CCH + c) * NV + v];
    rs1[idx] = 1.f / (s + EPSV);
}

__global__ void rowsum_inv_k(const float* __restrict__ A, const float* __restrict__ rs1,
                             float* __restrict__ rs2, int B, int NO, int NV) {
    int row = blockIdx.x * (blockDim.x >> 6) + (threadIdx.x >> 6);
    int lane = threadIdx.x & 63;
    if (row >= B * NO) return;
    int b = row / NO;
    const float* Ar = A + (size_t)row * NV;
    const float* r1 = rs1 + (size_t)b * NV;
    float s = 0.f;
    for (int v = lane; v < NV; v += 64) s += Ar[v] * r1[v];
    for (int off = 32; off; off >>= 1) s += __shfl_xor(s, off, 64);
    if (lane == 0) rs2[row] = 1.f / (s + EPSV);
}

// ---------------- fused GAT h-GEMM + score vectors (vis+obj in one launch) ----------
__global__ __launch_bounds__(128)
void gath2_k(GathP V, GathP O, int GV) {
    extern __shared__ float xs[];
    int bid = blockIdx.x;
    const GathP& P = (bid < GV) ? V : O;
    int row0 = ((bid < GV) ? bid : bid - GV) * 8;
    int t = threadIdx.x;
    int K = P.K, rows = P.rows;
    int K4 = K >> 2;
    for (int l = t; l < 8 * K4; l += 128) {
        int r = l / K4, c4 = l - r * K4;
        int row = row0 + r;
        float4 v = make_float4(0.f, 0.f, 0.f, 0.f);
        if (row < rows) v = ((const float4*)(P.X + (size_t)row * K))[c4];
        ((float4*)&xs[(size_t)r * K])[c4] = v;
    }
    __syncthreads();
    int wv = t >> 6, tt = t & 63, rb = wv * 4;
    float a0[4] = {0.f, 0.f, 0.f, 0.f}, a1v[4] = {0.f, 0.f, 0.f, 0.f};
#pragma unroll 4
    for (int k = 0; k < K; ++k) {
        float w0 = P.W[(size_t)k * HD + tt];
        float w1 = P.W[(size_t)k * HD + tt + 64];
#pragma unroll
        for (int r = 0; r < 4; ++r) {
            float x = xs[(size_t)(rb + r) * K + k];
            a0[r] = fmaf(x, w0, a0[r]);
            a1v[r] = fmaf(x, w1, a1v[r]);
        }
    }
    float A1 = P.a1[tt], A1b = P.a1[tt + 64], A2 = P.a2[tt], A2b = P.a2[tt + 64];
#pragma unroll
    for (int r = 0; r < 4; ++r) {
        int row = row0 + rb + r;
        if (row < rows) {
            P.h[(size_t)row * HD + tt]      = a0[r];
            P.h[(size_t)row * HD + tt + 64] = a1v[r];
        }
        float p = a0[r] * A1 + a1v[r] * A1b;
        float q = a0[r] * A2 + a1v[r] * A2b;
#pragma unroll
        for (int off = 32; off; off >>= 1) {
            p += __shfl_xor(p, off, 64);
            q += __shfl_xor(q, off, 64);
        }
        if (tt == 0 && row < rows) { P.sa[row] = p; P.sb[row] = q; }
    }
}

// ---------------- fused per-batch sb max ----------------
__global__ __launch_bounds__(256)
void sbmax2_k(const float* __restrict__ sbV, float* __restrict__ smV,
              const float* __restrict__ sbO, float* __restrict__ smO,
              int NV, int NO) {
    __shared__ float red[256];
    int b0 = blockIdx.x, t = threadIdx.x;
    const float* sb; float* out; int N;
    if (b0 < 8) { sb = sbV + (size_t)b0 * NV; out = smV + b0; N = NV; }
    else        { sb = sbO + (size_t)(b0 - 8) * NO; out = smO + (b0 - 8); N = NO; }
    float m = -INFINITY;
    for (int j = t; j < N; j += 256) m = fmaxf(m, sb[j]);
    red[t] = m; __syncthreads();
    for (int s = 128; s; s >>= 1) {
        if (t < s) red[t] = fmaxf(red[t], red[t + s]);
        __syncthreads();
    }
    if (t == 0) *out = red[0];
}

// ---------------- 256-thread tile FMA: 4 rows x 8 channels per thread ----------------
__device__ __forceinline__ void tile_fma256(const float (*hs)[HD], const float (*ws)[WP],
                                            int rg, int c0, float acc[4][8]) {
#pragma unroll 8
    for (int jl = 0; jl < JT; ++jl) {
        float4 h0 = *(const float4*)&hs[jl][c0];
        float4 h1 = *(const float4*)&hs[jl][c0 + 64];
        float4 w4 = *(const float4*)&ws[jl][rg * 4];
        float wq[4] = {w4.x, w4.y, w4.z, w4.w};
#pragma unroll
        for (int q = 0; q < 4; ++q) {
            float w = wq[q];
            acc[q][0] = fmaf(w, h0.x, acc[q][0]);
            acc[q][1] = fmaf(w, h0.y, acc[q][1]);
            acc[q][2] = fmaf(w, h0.z, acc[q][2]);
            acc[q][3] = fmaf(w, h0.w, acc[q][3]);
            acc[q][4] = fmaf(w, h1.x, acc[q][4]);
            acc[q][5] = fmaf(w, h1.y, acc[q][5]);
            acc[q][6] = fmaf(w, h1.z, acc[q][6]);
            acc[q][7] = fmaf(w, h1.w, acc[q][7]);
        }
    }
}

__device__ __forceinline__ void part_store256(float* __restrict__ pp, size_t base,
                                              int i0, int N, int rg, int c0,
                                              float acc[4][8]) {
#pragma unroll
    for (int q = 0; q < 4; ++q) {
        int i = i0 + rg * 4 + q;
        if (i >= N) continue;
        float* op = pp + base + (size_t)i * HD;
        *(float4*)&op[c0]      = make_float4(acc[q][0], acc[q][1], acc[q][2], acc[q][3]);
        *(float4*)&op[c0 + 64] = make_float4(acc[q][4], acc[q][5], acc[q][6], acc[q][7]);
    }
}

struct SharedTile { float hs[2][JT][HD]; float ws[2][JT][WP]; };

// ---------------- fused GAT aggregation (vis+obj), pipelined, 1 barrier/tile --------
struct SharedAgg { SharedTile tl; float sa_s[IT]; float m_s[IT]; };

__device__ void agg_body(SharedAgg& sm, const AggP& P, int lbid) {
    int tiles = P.tiles;
    int split = lbid / (8 * tiles);
    int rem = lbid - split * 8 * tiles;
    int b = rem / tiles;
    int i0 = (rem - b * tiles) * IT;
    int N = P.N;
    int j_begin = split * P.tps * JT;
    if (j_begin >= N) return;
    int j_end = j_begin + P.tps * JT;
    if (j_end > N) j_end = N;
    int T = (j_end - j_begin + JT - 1) / JT;
    int t = threadIdx.x;
    if (t < IT) {
        int i = i0 + t;
        float s = (i < N) ? P.sa[(size_t)b * N + i] : 0.f;
        sm.sa_s[t] = s;
        float e = s + P.sm[b];
        sm.m_s[t] = e > 0.f ? e : 0.2f * e;
    }
    __syncthreads();
    int rg = t >> 4, c0 = (t & 15) * 4;
    int il = t >> 2, j4 = (t & 3) * 4;
    float acc[4][8];
#pragma unroll
    for (int q = 0; q < 4; ++q)
#pragma unroll
        for (int x = 0; x < 8; ++x) acc[q][x] = 0.f;
    float zacc = 0.f;
    const float* adjb = P.adj + ((size_t)b * N + i0) * N;
    const float* hb = P.h + (size_t)b * N * HD;
    const float* sbb = P.sb + (size_t)b * N;
    int irow = i0 + il;
    stage_tile_async(hb + (size_t)j_begin * HD, &sm.tl.hs[0][0][0], t);
    float4 a4[2], s4[2];
#pragma unroll
    for (int k = 0; k < 2; ++k) {
        int j = j_begin + j4 + k * 16;
        float4 av = make_float4(0.f,0.f,0.f,0.f), sv = make_float4(0.f,0.f,0.f,0.f);
        if (irow < N) {
            if (j + 3 < N) {
                av = *(const float4*)&adjb[(size_t)il * N + j];
                sv = *(const float4*)&sbb[j];
            } else {
                float* ap = (float*)&av; float* sp = (float*)&sv;
                for (int r = 0; r < 4; ++r)
                    if (j + r < N) { ap[r] = adjb[(size_t)il * N + j + r]; sp[r] = sbb[j + r]; }
            }
        }
        a4[k] = av; s4[k] = sv;
    }
    for (int tt = 0; tt < T; ++tt) {
        int cur = tt & 1;
        float sai = sm.sa_s[il], m = sm.m_s[il];
#pragma unroll
        for (int k = 0; k < 2; ++k) {
            float av[4] = {a4[k].x, a4[k].y, a4[k].z, a4[k].w};
            float sv[4] = {s4[k].x, s4[k].y, s4[k].z, s4[k].w};
#pragma unroll
            for (int r = 0; r < 4; ++r) {
                float e = sai + sv[r];
                e = e > 0.f ? e : 0.2f * e;
                sm.tl.ws[cur][j4 + r + k * 16][il] = av[r] > 0.f ? __expf(e - m) : 0.f;
            }
        }
        __syncthreads();
        if (tt + 1 < T) {
            int jn = j_begin + (tt + 1) * JT;
            stage_tile_async(hb + (size_t)jn * HD, &sm.tl.hs[1 - cur][0][0], t);
#pragma unroll
            for (int k = 0; k < 2; ++k) {
                int j = jn + j4 + k * 16;
                float4 av = make_float4(0.f,0.f,0.f,0.f), sv = make_float4(0.f,0.f,0.f,0.f);
                if (irow < N) {
                    if (j + 3 < N) {
                        av = *(const float4*)&adjb[(size_t)il * N + j];
                        sv = *(const float4*)&sbb[j];
                    } else {
                        float* ap = (float*)&av; float* sp = (float*)&sv;
                        for (int r = 0; r < 4; ++r)
                            if (j + r < N) { ap[r] = adjb[(size_t)il * N + j + r]; sp[r] = sbb[j + r]; }
                    }
                }
                a4[k] = av; s4[k] = sv;
            }
        }
        tile_fma256(sm.tl.hs[cur], sm.tl.ws[cur], rg, c0, acc);
        if (t < IT) {
            float z = 0.f;
#pragma unroll 8
            for (int jl = 0; jl < JT; ++jl) z += sm.tl.ws[cur][jl][t];
            zacc += z;
        }
    }
    size_t rowsTot = (size_t)8 * N;
    part_store256(P.pp, ((size_t)split * rowsTot + (size_t)b * N) * HD, i0, N, rg, c0, acc);
    if (t < IT && i0 + t < N)
        P.zp[(size_t)split * rowsTot + (size_t)b * N + i0 + t] = zacc;
}

__global__ __launch_bounds__(256)
void agg2_k(AggP V, AggP O, int GVb) {
    __shared__ SharedAgg sm;
    int bid = blockIdx.x;
    if (bid < GVb) agg_body(sm, V, bid);
    else           agg_body(sm, O, bid - GVb);
}

// ---------------- fused cross (vo + ov), pipelined ----------------
__device__ void cross_vo_body(SharedTile& sm, const CrossP& P, int lbid) {
    int tiles = P.tiles;
    int split = lbid / (8 * tiles);
    int rem = lbid - split * 8 * tiles;
    int b = rem / tiles;
    int i0 = (rem - b * tiles) * IT;
    int NVl = P.iN, NOl = P.jN;
    int j_begin = split * P.tps * JT;
    if (j_begin >= NOl) return;
    int j_end = j_begin + P.tps * JT;
    if (j_end > NOl) j_end = NOl;
    int T = (j_end - j_begin + JT - 1) / JT;
    int t = threadIdx.x;
    int rg = t >> 4, c0 = (t & 15) * 4;
    int il = t & 63, jlb = t >> 6;
    float acc[4][8];
#pragma unroll
    for (int q = 0; q < 4; ++q)
#pragma unroll
        for (int x = 0; x < 8; ++x) acc[q][x] = 0.f;
    const float* Ab = P.A + (size_t)b * NOl * NVl;
    const float* srcb = P.src + (size_t)b * NOl * HD;
    int v = i0 + il;
    float w8[8];
    stage_tile_async(srcb + (size_t)j_begin * HD, &sm.hs[0][0][0], t);
#pragma unroll
    for (int k = 0; k < 8; ++k) {
        int o = j_begin + jlb + k * 4;
        w8[k] = (v < NVl && o < NOl) ? Ab[(size_t)o * NVl + v] : 0.f;
    }
    for (int tt = 0; tt < T; ++tt) {
        int cur = tt & 1;
#pragma unroll
        for (int k = 0; k < 8; ++k) sm.ws[cur][jlb + k * 4][il] = w8[k];
        __syncthreads();
        if (tt + 1 < T) {
            int jn = j_begin + (tt + 1) * JT;
            stage_tile_async(srcb + (size_t)jn * HD, &sm.hs[1 - cur][0][0], t);
#pragma unroll
            for (int k = 0; k < 8; ++k) {
                int o = jn + jlb + k * 4;
                w8[k] = (v < NVl && o < NOl) ? Ab[(size_t)o * NVl + v] : 0.f;
            }
        }
        tile_fma256(sm.hs[cur], sm.ws[cur], rg, c0, acc);
    }
    size_t rowsTot = (size_t)8 * NVl;
    part_store256(P.pp, ((size_t)split * rowsTot + (size_t)b * NVl) * HD, i0, NVl, rg, c0, acc);
}

__device__ void cross_ov_body(SharedTile& sm, const CrossP& P, int lbid) {
    int tiles = P.tiles;
    int split = lbid / (8 * tiles);
    int rem = lbid - split * 8 * tiles;
    int b = rem / tiles;
    int i0 = (rem - b * tiles) * IT;
    int NOl = P.iN, NVl = P.jN;
    int j_begin = split * P.tps * JT;
    if (j_begin >= NVl) return;
    int j_end = j_begin + P.tps * JT;
    if (j_end > NVl) j_end = NVl;
    int T = (j_end - j_begin + JT - 1) / JT;
    int t = threadIdx.x;
    int rg = t >> 4, c0 = (t & 15) * 4;
    int il = t >> 2, j4 = (t & 3) * 4;
    float acc[4][8];
#pragma unroll
    for (int q = 0; q < 4; ++q)
#pragma unroll
        for (int x = 0; x < 8; ++x) acc[q][x] = 0.f;
    const float* Ab = P.A + (size_t)b * NOl * NVl;
    const float* srcb = P.src + (size_t)b * NVl * HD;
    const float* r1b = P.rs1 + (size_t)b * NVl;
    int orow = i0 + il;
    float4 a4[2], r4[2];
    stage_tile_async(srcb + (size_t)j_begin * HD, &sm.hs[0][0][0], t);
#pragma unroll
    for (int k = 0; k < 2; ++k) {
        int vv = j_begin + j4 + k * 16;
        float4 av = make_float4(0.f,0.f,0.f,0.f), rv = make_float4(0.f,0.f,0.f,0.f);
        if (orow < NOl) {
            if (vv + 3 < NVl) {
                av = *(const float4*)&Ab[(size_t)orow * NVl + vv];
                rv = *(const float4*)&r1b[vv];
            } else {
                float* ap = (float*)&av; float* rp = (float*)&rv;
                for (int r = 0; r < 4; ++r)
                    if (vv + r < NVl) { ap[r] = Ab[(size_t)orow * NVl + vv + r]; rp[r] = r1b[vv + r]; }
            }
        }
        a4[k] = av; r4[k] = rv;
    }
    for (int tt = 0; tt < T; ++tt) {
        int cur = tt & 1;
#pragma unroll
        for (int k = 0; k < 2; ++k) {
            float wv[4] = {a4[k].x * r4[k].x, a4[k].y * r4[k].y,
                           a4[k].z * r4[k].z, a4[k].w * r4[k].w};
#pragma unroll
            for (int r = 0; r < 4; ++r) sm.ws[cur][j4 + r + k * 16][il] = wv[r];
        }
        __syncthreads();
        if (tt + 1 < T) {
            int jn = j_begin + (tt + 1) * JT;
            stage_tile_async(srcb + (size_t)jn * HD, &sm.hs[1 - cur][0][0], t);
#pragma unroll
            for (int k = 0; k < 2; ++k) {
                int vv = jn + j4 + k * 16;
                float4 av = make_float4(0.f,0.f,0.f,0.f), rv = make_float4(0.f,0.f,0.f,0.f);
                if (orow < NOl) {
                    if (vv + 3 < NVl) {
                        av = *(const float4*)&Ab[(size_t)orow * NVl + vv];
                        rv = *(const float4*)&r1b[vv];
                    } else {
                        float* ap = (float*)&av; float* rp = (float*)&rv;
                        for (int r = 0; r < 4; ++r)
                            if (vv + r < NVl) { ap[r] = Ab[(size_t)orow * NVl + vv + r]; rp[r] = r1b[vv + r]; }
                    }
                }
                a4[k] = av; r4[k] = rv;
            }
        }
        tile_fma256(sm.hs[cur], sm.ws[cur], rg, c0, acc);
    }
    size_t rowsTot = (size_t)8 * NOl;
    part_store256(P.pp, ((size_t)split * rowsTot + (size_t)b * NOl) * HD, i0, NOl, rg, c0, acc);
}

__global__ __launch_bounds__(256)
void cross2_k(CrossP VO, CrossP OV, int GVOb) {
    __shared__ SharedTile sm;
    int bid = blockIdx.x;
    if (bid < GVOb) cross_vo_body(sm, VO, bid);
    else            cross_ov_body(sm, OV, bid - GVOb);
}

// ---------------- fused finalize GAT: sum S partials, /Z, relu ----------------
__global__ __launch_bounds__(256)
void fin2_k(FinP V, FinP O, int GVb) {
    int bid = blockIdx.x;
    const FinP& P = (bid < GVb) ? V : O;
    int idx = ((bid < GVb) ? bid : bid - GVb) * 256 + threadIdx.x;
    int rows = P.rows;
    int row = idx >> 5;
    if (row >= rows) return;
    float4 v = make_float4(0.f, 0.f, 0.f, 0.f);
    for (int s = 0; s < P.S; ++s) {
        float4 p = ((const float4*)P.pp)[((size_t)s * rows + row) * 32 + (idx & 31)];
        v.x += p.x; v.y += p.y; v.z += p.z; v.w += p.w;
    }
    float z = 0.f;
    for (int s = 0; s < P.S; ++s) z += P.zp[(size_t)s * rows + row];
    float sc = 1.f / z;
    v.x = fmaxf(v.x * sc, 0.f); v.y = fmaxf(v.y * sc, 0.f);
    v.z = fmaxf(v.z * sc, 0.f); v.w = fmaxf(v.w * sc, 0.f);
    ((float4*)P.out)[idx] = v;
}

// ---------------- fused MLP: out = (relu(x@W1+b1))@W2 + b2 + res ----------------
__global__ __launch_bounds__(128)
void mlp2_k(MlpP V, MlpP O, int GVb) {
    __shared__ float xs[8][HD];
    __shared__ float hh[8][HD];
    int bid = blockIdx.x;
    const MlpP& P = (bid < GVb) ? V : O;
    int row0 = ((bid < GVb) ? bid : bid - GVb) * 8;
    int rows = P.rows;
    int t = threadIdx.x;
    for (int l = t; l < 8 * 32; l += 128) {
        int r = l >> 5, c4 = l & 31;
        int row = row0 + r;
        float4 v = make_float4(0.f, 0.f, 0.f, 0.f);
        if (row < rows) {
            for (int s = 0; s < P.S; ++s) {
                float4 p = ((const float4*)P.pp)[((size_t)s * rows + row) * 32 + c4];
                v.x += p.x; v.y += p.y; v.z += p.z; v.w += p.w;
            }
            float sc = P.scale[row];
            v.x *= sc; v.y *= sc; v.z *= sc; v.w *= sc;
        }
        ((float4*)&xs[r][0])[c4] = v;
    }
    __syncthreads();
    int wv = t >> 6, tt = t & 63, rb = wv * 4;
    float a0[4] = {0.f, 0.f, 0.f, 0.f}, a1v[4] = {0.f, 0.f, 0.f, 0.f};
#pragma unroll 4
    for (int k = 0; k < HD; ++k) {
        float w0 = P.W1[(size_t)k * HD + tt];
        float w1 = P.W1[(size_t)k * HD + tt + 64];
#pragma unroll
        for (int r = 0; r < 4; ++r) {
            float x = xs[rb + r][k];
            a0[r] = fmaf(x, w0, a0[r]);
            a1v[r] = fmaf(x, w1, a1v[r]);
        }
    }
    float bb0 = P.b1[tt], bb1 = P.b1[tt + 64];
#pragma unroll
    for (int r = 0; r < 4; ++r) {
        hh[rb + r][tt]      = fmaxf(a0[r] + bb0, 0.f);
        hh[rb + r][tt + 64] = fmaxf(a1v[r] + bb1, 0.f);
    }
    __syncthreads();
    float c0a[4] = {0.f, 0.f, 0.f, 0.f}, c1a[4] = {0.f, 0.f, 0.f, 0.f};
#pragma unroll 4
    for (int k = 0; k < HD; ++k) {
        float w0 = P.W2[(size_t)k * HD + tt];
        float w1 = P.W2[(size_t)k * HD + tt + 64];
#pragma unroll
        for (int r = 0; r < 4; ++r) {
            float x = hh[rb + r][k];
            c0a[r] = fmaf(x, w0, c0a[r]);
            c1a[r] = fmaf(x, w1, c1a[r]);
        }
    }
    float d0 = P.b2[tt], d1 = P.b2[tt + 64];
#pragma unroll
    for (int r = 0; r < 4; ++r) {
        int row = row0 + rb + r;
        if (row >= rows) continue;
        P.out[(size_t)row * HD + tt]      = c0a[r] + d0 + P.res[(size_t)row * HD + tt];
        P.out[(size_t)row * HD + tt + 64] = c1a[r] + d1 + P.res[(size_t)row * HD + tt + 64];
    }
}

// ---------------- output projection ----------------
template<int RELU, int BIAS, int RES>
__global__ __launch_bounds__(128)
void linear_k(const float* __restrict__ X, const float* __restrict__ W,
              const float* __restrict__ bias, const float* __restrict__ res,
              float* __restrict__ out, int rows, int K, int Dout) {
    __shared__ float xs[4][512];
    int row0 = blockIdx.x * 4;
    int t = threadIdx.x;
    int K4 = K >> 2;
    for (int l = t; l < 4 * K4; l += 128) {
        int r = l / K4, c4 = l - r * K4;
        float4 val = make_float4(0.f, 0.f, 0.f, 0.f);
        if (row0 + r < rows) val = ((const float4*)(X + (size_t)(row0 + r) * K))[c4];
        ((float4*)&xs[r][0])[c4] = val;
    }
    __syncthreads();
    int chunk = Dout < 256 ? Dout : 256;
    int half = chunk >> 1;
    if (t >= half) return;
    int c0 = blockIdx.y * chunk + t;
    int c1 = c0 + half;
    float a00 = 0, a01 = 0, a02 = 0, a03 = 0, a10 = 0, a11 = 0, a12 = 0, a13 = 0;
#pragma unroll 4
    for (int k = 0; k < K; ++k) {
        float w0 = W[(size_t)k * Dout + c0];
        float w1 = W[(size_t)k * Dout + c1];
        float x0 = xs[0][k], x1 = xs[1][k], x2 = xs[2][k], x3 = xs[3][k];
        a00 = fmaf(x0, w0, a00); a01 = fmaf(x1, w0, a01);
        a02 = fmaf(x2, w0, a02); a03 = fmaf(x3, w0, a03);
        a10 = fmaf(x0, w1, a10); a11 = fmaf(x1, w1, a11);
        a12 = fmaf(x2, w1, a12); a13 = fmaf(x3, w1, a13);
    }
    float accs[2][4] = {{a00, a01, a02, a03}, {a10, a11, a12, a13}};
    int cs[2] = {c0, c1};
    for (int h = 0; h < 2; ++h) {
        float bv = BIAS ? bias[cs[h]] : 0.f;
        for (int r = 0; r < 4; ++r) {
            int row = row0 + r;
            if (row >= rows) continue;
            float v = accs[h][r] + bv;
            if (RES) v += res[(size_t)row * Dout + cs[h]];
            if (RELU) v = fmaxf(v, 0.f);
            out[(size_t)row * Dout + cs[h]] = v;
        }
    }
}

// ---------------- host launcher ----------------
extern "C" void kernel_launch(void* const* d_in, const int* in_sizes, int n_in,
                              void* d_out, int out_size, void* d_ws, size_t ws_size,
                              hipStream_t stream) {
    const int B = 8, NV = 500, NO = 1500, DV = 512, DO = 32;
    const float* vis_memory = (const float*)d_in[0];
    const float* obj_memory = (const float*)d_in[1];
    const float* vis_adj    = (const float*)d_in[2];
    const float* obj_adj    = (const float*)d_in[3];
    const float* A_OV       = (const float*)d_in[4];
    const float* Wv1  = (const float*)d_in[5];
    const float* av1a = (const float*)d_in[6];
    const float* av1b = (const float*)d_in[7];
    const float* Wv2  = (const float*)d_in[8];
    const float* av2a = (const float*)d_in[9];
    const float* av2b = (const float*)d_in[10];
    const float* Wo1  = (const float*)d_in[11];
    const float* ao1a = (const float*)d_in[12];
    const float* ao1b = (const float*)d_in[13];
    const float* Wo2  = (const float*)d_in[14];
    const float* ao2a = (const float*)d_in[15];
    const float* ao2b = (const float*)d_in[16];
    const float* g2o_W1 = (const float*)d_in[17];
    const float* g2o_b1 = (const float*)d_in[18];
    const float* g2o_W2 = (const float*)d_in[19];
    const float* g2o_b2 = (const float*)d_in[20];
    const float* o2g_W1 = (const float*)d_in[21];
    const float* o2g_b1 = (const float*)d_in[22];
    const float* o2g_W2 = (const float*)d_in[23];
    const float* o2g_b2 = (const float*)d_in[24];
    const float* img_W = (const float*)d_in[25];
    const float* img_b = (const float*)d_in[26];
    const float* obj_W = (const float*)d_in[27];
    const float* obj_b = (const float*)d_in[28];

    float* wsp = (float*)d_ws;
    size_t off = 0;
    auto alloc = [&](size_t n) { float* p = wsp + off; off += n; return p; };
    float* rs1   = alloc(B * NV);
    float* rs2   = alloc(B * NO);
    float* saV   = alloc(B * NV);
    float* sbV   = alloc(B * NV);
    float* smV   = alloc(B);
    float* saO   = alloc(B * NO);
    float* sbO   = alloc(B * NO);
    float* smO   = alloc(B);
    float* s1p   = alloc((size_t)B * CCH * NV);
    float* hv    = alloc((size_t)B * NV * HD);
    float* ho    = alloc((size_t)B * NO * HD);
    float* v1    = alloc((size_t)B * NV * HD);
    float* o1    = alloc((size_t)B * NO * HD);
    float* visb  = alloc((size_t)B * NV * HD);
    float* objb  = alloc((size_t)B * NO * HD);
    float* ppV   = alloc((size_t)8 * B * NV * HD);
    float* zpV   = alloc((size_t)8 * B * NV);
    float* ppO   = alloc((size_t)4 * B * NO * HD);
    float* zpO   = alloc((size_t)4 * B * NO);
    alloc(16384);                                    // tail pad for async OOB reads

    colsum_part_k<<<dim3((NV + 255) / 256, CCH, B), 256, 0, stream>>>(A_OV, s1p, B, NO, NV);
    colsum_fin_k<<<dim3((B * NV + 255) / 256), 256, 0, stream>>>(s1p, rs1, B, NV);
    rowsum_inv_k<<<dim3((B * NO + 3) / 4), 256, 0, stream>>>(A_OV, rs1, rs2, B, NO, NV);

    // geometry (IT=64, JT=32):
    const int tilesV = 8, tilesO = 24;               // ceil(500/64), ceil(1500/64)
    const int SV = 8, SO = 4, SVO = 8, SOV = 4;
    const int tpsV = 2;    // ceil(ceil(500/32)/8)
    const int tpsO = 12;   // ceil(ceil(1500/32)/4)
    const int tpsVO = 6;   // ceil(ceil(1500/32)/8)
    const int tpsOV = 4;   // ceil(ceil(500/32)/4)
    const int G_AGG_V = B * tilesV * SV;             // 512
    const int G_AGG_O = B * tilesO * SO;             // 768
    const int G_CR_VO = B * tilesV * SVO;            // 512
    const int G_CR_OV = B * tilesO * SOV;            // 768
    const int G_GATH_V = B * NV / 8;                 // 500
    const int G_GATH_O = B * NO / 8;                 // 1500
    const int G_FIN_V = B * NV * 32 / 256;           // 500
    const int G_FIN_O = B * NO * 32 / 256;           // 1500

    auto layer = [&](const float* Xv, int Kv, const float* Wv_, const float* a1v_, const float* a2v_,
                     const float* Xo, int Ko, const float* Wo_, const float* a1o_, const float* a2o_,
                     float* visout, float* objout) {
        GathP gv{Xv, Wv_, a1v_, a2v_, hv, saV, sbV, B * NV, Kv};
        GathP go{Xo, Wo_, a1o_, a2o_, ho, saO, sbO, B * NO, Ko};
        int maxK = Kv > Ko ? Kv : Ko;
        gath2_k<<<G_GATH_V + G_GATH_O, 128, 8 * maxK * 4, stream>>>(gv, go, G_GATH_V);
        sbmax2_k<<<16, 256, 0, stream>>>(sbV, smV, sbO, smO, NV, NO);
        AggP av{vis_adj, hv, saV, sbV, smV, ppV, zpV, NV, tilesV, tpsV};
        AggP ao{obj_adj, ho, saO, sbO, smO, ppO, zpO, NO, tilesO, tpsO};
        agg2_k<<<G_AGG_V + G_AGG_O, THR, 0, stream>>>(av, ao, G_AGG_V);
        FinP fv{ppV, zpV, v1, B * NV, SV};
        FinP fo{ppO, zpO, o1, B * NO, SO};
        fin2_k<<<G_FIN_V + G_FIN_O, 256, 0, stream>>>(fv, fo, G_FIN_V);
        CrossP cvo{A_OV, o1, nullptr, ppV, NV, NO, tilesV, tpsVO};
        CrossP cov{A_OV, v1, rs1, ppO, NO, NV, tilesO, tpsOV};
        cross2_k<<<G_CR_VO + G_CR_OV, THR, 0, stream>>>(cvo, cov, G_CR_VO);
        MlpP mv{ppV, rs1, SVO, o2g_W1, o2g_b1, o2g_W2, o2g_b2, v1, visout, B * NV};
        MlpP mo{ppO, rs2, SOV, g2o_W1, g2o_b1, g2o_W2, g2o_b2, o1, objout, B * NO};
        mlp2_k<<<G_GATH_V + G_GATH_O, 128, 0, stream>>>(mv, mo, G_GATH_V);
    };

    // layer 1
    layer(vis_memory, DV, Wv1, av1a, av1b, obj_memory, DO, Wo1, ao1a, ao1b, visb, objb);
    // layer 2
    layer(visb, HD, Wv2, av2a, av2b, objb, HD, Wo2, ao2a, ao2b, visb, objb);

    // output projections
    float* vis_out = (float*)d_out;
    float* obj_out = vis_out + (size_t)B * NV * DV;
    linear_k<0, 1, 0><<<dim3((B * NV + 3) / 4, (DV + 255) / 256), 128, 0, stream>>>(
        visb, img_W, img_b, nullptr, vis_out, B * NV, HD, DV);
    linear_k<0, 1, 0><<<dim3((B * NO + 3) / 4, 1), 128, 0, stream>>>(
        objb, obj_W, obj_b, nullptr, obj_out, B * NO, HD, DO);
}

// Round 9
// 650.840 us; speedup vs baseline: 1.2702x; 1.0918x over previous
//
#include <hip/hip_runtime.h>
#include <math.h>

#define EPSV 1e-5f
#define HD 128
#define IT 64
#define JT 32
#define WP 68
#define CCH 16
#define THR 256

typedef __attribute__((address_space(3))) uint32_t lds_u32_t;
typedef __attribute__((address_space(1))) uint32_t gbl_u32_t;
typedef __attribute__((ext_vector_type(8))) short bf16x8;
typedef __attribute__((ext_vector_type(4))) float f32x4;

__device__ __forceinline__ void async_copy16(const float* g, float* l) {
    __builtin_amdgcn_global_load_lds((const gbl_u32_t*)g, (lds_u32_t*)l, 16, 0, 0);
}

// stage a JT x HD fp32 tile (16 KB) global -> LDS via async DMA (256 threads)
__device__ __forceinline__ void stage_tile_async(const float* gsrc, float* lds, int t) {
    int wv = t >> 6, lane = t & 63;
#pragma unroll
    for (int it = 0; it < 4; ++it) {
        int c = it * 4 + wv;
        async_copy16(gsrc + c * 256 + lane * 4, lds + c * 256);
    }
}

// stage an 8 KB bf16 tile global -> LDS via async DMA (256 threads, 2 insts)
__device__ __forceinline__ void stage_8k(const void* g, void* l, int t) {
    const float* gf = (const float*)g; float* lf = (float*)l;
    async_copy16(gf + t * 4, lf + t * 4);
    async_copy16(gf + t * 4 + 1024, lf + t * 4 + 1024);
}

__device__ __forceinline__ unsigned int f2bf(float f) {
    return __builtin_bit_cast(unsigned int, f) >> 16;
}

// ---------------- param structs for fused (vis+obj) launches ----------------
struct GathP { const float *X, *W, *a1, *a2; unsigned short* hT; float *sa, *sb;
               int rows, K, N, tilesJ; };
struct AggP  { const float *adj, *sa, *sb, *sm; const unsigned short* hT;
               float *pp, *zp; int N, tiles, tilesJ, tps; };
struct CrossP{ const float *A, *src, *rs1; float *pp; int iN, jN, tiles, tps; };
struct FinP  { const float *pp, *zp; float *out; int rows, S; };
struct MlpP  { const float *pp, *scale; int S; const float *W1, *b1, *W2, *b2, *res;
               float *out; int rows; };

// ---------------- normalization scale kernels ----------------

__global__ void colsum_part_k(const float* __restrict__ A, float* __restrict__ s1p,
                              int B, int NO, int NV) {
    int v = blockIdx.x * 256 + threadIdx.x;
    int c = blockIdx.y, b = blockIdx.z;
    if (v >= NV) return;
    int chunk = (NO + CCH - 1) / CCH;
    int o0 = c * chunk;
    int o1 = o0 + chunk; if (o1 > NO) o1 = NO;
    const float* Ab = A + (size_t)b * NO * NV + v;
    float s = 0.f;
    for (int o = o0; o < o1; ++o) s += Ab[(size_t)o * NV];
    s1p[((size_t)b * CCH + c) * NV + v] = s;
}

__global__ void colsum_fin_k(const float* __restrict__ s1p, float* __restrict__ rs1,
                             int B, int NV) {
    int idx = blockIdx.x * 256 + threadIdx.x;
    if (idx >= B * NV) return;
    int b = idx / NV, v = idx - b * NV;
    float s = 0.f;
    for (int c = 0; c < CCH; ++c) s += s1p[((size_t)b * CCH + c) * NV + v];
    rs1[idx] = 1.f / (s + EPSV);
}

__global__ void rowsum_inv_k(const float* __restrict__ A, const float* __restrict__ rs1,
                             float* __restrict__ rs2, int B, int NO, int NV) {
    int row = blockIdx.x * (blockDim.x >> 6) + (threadIdx.x >> 6);
    int lane = threadIdx.x & 63;
    if (row >= B * NO) return;
    int b = row / NO;
    const float* Ar = A + (size_t)row * NV;
    const float* r1 = rs1 + (size_t)b * NV;
    float s = 0.f;
    for (int v = lane; v < NV; v += 64) s += Ar[v] * r1[v];
    for (int off = 32; off; off >>= 1) s += __shfl_xor(s, off, 64);
    if (lane == 0) rs2[row] = 1.f / (s + EPSV);
}

// ---------------- fused GAT h-GEMM + score vectors; h emitted bf16-transposed ------
// hT layout: [b][jt][c:128][jl:32] bf16 — agg stages tiles via pure DMA.
__global__ __launch_bounds__(128)
void gath2_k(GathP V, GathP O, int GV) {
    extern __shared__ float xs[];
    int bid = blockIdx.x;
    const GathP& P = (bid < GV) ? V : O;
    int row0 = ((bid < GV) ? bid : bid - GV) * 8;
    int t = threadIdx.x;
    int K = P.K, rows = P.rows;
    int K4 = K >> 2;
    for (int l = t; l < 8 * K4; l += 128) {
        int r = l / K4, c4 = l - r * K4;
        int row = row0 + r;
        float4 v = make_float4(0.f, 0.f, 0.f, 0.f);
        if (row < rows) v = ((const float4*)(P.X + (size_t)row * K))[c4];
        ((float4*)&xs[(size_t)r * K])[c4] = v;
    }
    __syncthreads();
    int wv = t >> 6, tt = t & 63, rb = wv * 4;
    float a0[4] = {0.f, 0.f, 0.f, 0.f}, a1v[4] = {0.f, 0.f, 0.f, 0.f};
#pragma unroll 4
    for (int k = 0; k < K; ++k) {
        float w0 = P.W[(size_t)k * HD + tt];
        float w1 = P.W[(size_t)k * HD + tt + 64];
#pragma unroll
        for (int r = 0; r < 4; ++r) {
            float x = xs[(size_t)(rb + r) * K + k];
            a0[r] = fmaf(x, w0, a0[r]);
            a1v[r] = fmaf(x, w1, a1v[r]);
        }
    }
    float A1 = P.a1[tt], A1b = P.a1[tt + 64], A2 = P.a2[tt], A2b = P.a2[tt + 64];
#pragma unroll
    for (int r = 0; r < 4; ++r) {
        int row = row0 + rb + r;
        if (row < rows) {
            int b = row / P.N, nn = row - b * P.N;
            int jt = nn >> 5, jl = nn & 31;
            unsigned short* base = P.hT + ((size_t)(b * P.tilesJ + jt) * 128) * 32;
            base[(size_t)tt * 32 + jl]        = (unsigned short)f2bf(a0[r]);
            base[(size_t)(tt + 64) * 32 + jl] = (unsigned short)f2bf(a1v[r]);
        }
        float p = a0[r] * A1 + a1v[r] * A1b;
        float q = a0[r] * A2 + a1v[r] * A2b;
#pragma unroll
        for (int off = 32; off; off >>= 1) {
            p += __shfl_xor(p, off, 64);
            q += __shfl_xor(q, off, 64);
        }
        if (tt == 0 && row < rows) { P.sa[row] = p; P.sb[row] = q; }
    }
}

// ---------------- fused per-batch sb max ----------------
__global__ __launch_bounds__(256)
void sbmax2_k(const float* __restrict__ sbV, float* __restrict__ smV,
              const float* __restrict__ sbO, float* __restrict__ smO,
              int NV, int NO) {
    __shared__ float red[256];
    int b0 = blockIdx.x, t = threadIdx.x;
    const float* sb; float* out; int N;
    if (b0 < 8) { sb = sbV + (size_t)b0 * NV; out = smV + b0; N = NV; }
    else        { sb = sbO + (size_t)(b0 - 8) * NO; out = smO + (b0 - 8); N = NO; }
    float m = -INFINITY;
    for (int j = t; j < N; j += 256) m = fmaxf(m, sb[j]);
    red[t] = m; __syncthreads();
    for (int s = 128; s; s >>= 1) {
        if (t < s) red[t] = fmaxf(red[t], red[t + s]);
        __syncthreads();
    }
    if (t == 0) *out = red[0];
}

// ---------------- MFMA GAT aggregation (vis+obj fused) ----------------
// out[IT x HD] += P[IT x JT] @ H[JT x HD] per K-tile via mfma_f32_16x16x32_bf16.
// A-frag: A[m=lane&15][k=quad*8+i] (m120-verified); B-frag: B[k=quad*8+i][n=lane&15];
// C/D: col=lane&15, row=quad*4+reg (m89-verified).
struct SharedAggM {
    unsigned short hsT[2][128][32];    // [c][jl] bf16, DMA'd from hT
    unsigned short wsA[2][4][64][8];   // A-fragment order per wave
    float sa_s[IT], m_s[IT];
};

__device__ void agg_body(SharedAggM& sm, const AggP& P, int lbid) {
    int tiles = P.tiles;
    int split = lbid / (8 * tiles);
    int rem = lbid - split * 8 * tiles;
    int b = rem / tiles;
    int i0 = (rem - b * tiles) * IT;
    int N = P.N;
    int jt0 = split * P.tps;
    if (jt0 >= P.tilesJ) return;
    int jt1 = jt0 + P.tps; if (jt1 > P.tilesJ) jt1 = P.tilesJ;
    int T = jt1 - jt0;
    int t = threadIdx.x;
    if (t < IT) {
        int i = i0 + t;
        float s = (i < N) ? P.sa[(size_t)b * N + i] : 0.f;
        sm.sa_s[t] = s;
        float e = s + P.sm[b];
        sm.m_s[t] = e > 0.f ? e : 0.2f * e;
    }
    __syncthreads();
    int wv = t >> 6, lane = t & 63;
    // w-producer role: thread owns row il, j-offsets {j4..j4+3, j4+16..j4+19}
    int il = t >> 2, j4 = (t & 3) * 4;
    int q0 = j4 >> 3, i0w = j4 & 7, wrow = il & 15;
    // MFMA consumer role
    int nquad = lane >> 4, nlow = lane & 15;
    f32x4 acc[8];
#pragma unroll
    for (int nt = 0; nt < 8; ++nt)
#pragma unroll
        for (int r = 0; r < 4; ++r) acc[nt][r] = 0.f;
    float zacc = 0.f;
    const float* adjb = P.adj + ((size_t)b * N + i0) * N;
    const float* sbb = P.sb + (size_t)b * N;
    const unsigned short* hTb = P.hT + ((size_t)b * P.tilesJ + jt0) * 4096;
    int irow = i0 + il;
    // prologue: DMA tile0 + adj regs tile0
    stage_8k(hTb, &sm.hsT[0][0][0], t);
    float4 a4[2], s4[2];
#pragma unroll
    for (int k = 0; k < 2; ++k) {
        int j = jt0 * JT + j4 + k * 16;
        float4 av = make_float4(0.f,0.f,0.f,0.f), sv = make_float4(0.f,0.f,0.f,0.f);
        if (irow < N) {
            if (j + 3 < N) {
                av = *(const float4*)&adjb[(size_t)il * N + j];
                sv = *(const float4*)&sbb[j];
            } else {
                float* ap = (float*)&av; float* sp = (float*)&sv;
                for (int r = 0; r < 4; ++r)
                    if (j + r < N) { ap[r] = adjb[(size_t)il * N + j + r]; sp[r] = sbb[j + r]; }
            }
        }
        a4[k] = av; s4[k] = sv;
    }
    for (int tt = 0; tt < T; ++tt) {
        int cur = tt & 1;
        float sai = sm.sa_s[il], m = sm.m_s[il];
#pragma unroll
        for (int k = 0; k < 2; ++k) {
            float av[4] = {a4[k].x, a4[k].y, a4[k].z, a4[k].w};
            float sv[4] = {s4[k].x, s4[k].y, s4[k].z, s4[k].w};
            float w[4];
#pragma unroll
            for (int r = 0; r < 4; ++r) {
                float e = sai + sv[r];
                e = e > 0.f ? e : 0.2f * e;
                w[r] = av[r] > 0.f ? __expf(e - m) : 0.f;
                zacc += w[r];
            }
            unsigned int lo = f2bf(w[0]) | (__builtin_bit_cast(unsigned int, w[1]) & 0xFFFF0000u);
            unsigned int hi = f2bf(w[2]) | (__builtin_bit_cast(unsigned int, w[3]) & 0xFFFF0000u);
            uint2 pk = make_uint2(lo, hi);
            *(uint2*)&sm.wsA[cur][wv][wrow + 16 * (q0 + 2 * k)][i0w] = pk;
        }
        __syncthreads();   // wsA[cur] visible; hsT[cur] DMA drained
        if (tt + 1 < T) {
            stage_8k(hTb + (size_t)(tt + 1) * 4096, &sm.hsT[1 - cur][0][0], t);
#pragma unroll
            for (int k = 0; k < 2; ++k) {
                int j = (jt0 + tt + 1) * JT + j4 + k * 16;
                float4 av = make_float4(0.f,0.f,0.f,0.f), sv = make_float4(0.f,0.f,0.f,0.f);
                if (irow < N) {
                    if (j + 3 < N) {
                        av = *(const float4*)&adjb[(size_t)il * N + j];
                        sv = *(const float4*)&sbb[j];
                    } else {
                        float* ap = (float*)&av; float* sp = (float*)&sv;
                        for (int r = 0; r < 4; ++r)
                            if (j + r < N) { ap[r] = adjb[(size_t)il * N + j + r]; sp[r] = sbb[j + r]; }
                    }
                }
                a4[k] = av; s4[k] = sv;
            }
        }
        bf16x8 afrag = *(const bf16x8*)&sm.wsA[cur][wv][lane][0];
#pragma unroll
        for (int nt = 0; nt < 8; ++nt) {
            bf16x8 bfrag = *(const bf16x8*)&sm.hsT[cur][nt * 16 + nlow][nquad * 8];
            acc[nt] = __builtin_amdgcn_mfma_f32_16x16x32_bf16(afrag, bfrag, acc[nt], 0, 0, 0);
        }
    }
    // z: reduce over the 4 threads sharing row il
    zacc += __shfl_xor(zacc, 1, 64);
    zacc += __shfl_xor(zacc, 2, 64);
    size_t rowsTot = (size_t)8 * N;
    float* pp = P.pp + ((size_t)split * rowsTot + (size_t)b * N) * HD;
#pragma unroll
    for (int nt = 0; nt < 8; ++nt)
#pragma unroll
        for (int r = 0; r < 4; ++r) {
            int row = i0 + wv * 16 + nquad * 4 + r;
            if (row < N) pp[(size_t)row * HD + nt * 16 + nlow] = acc[nt][r];
        }
    if ((t & 3) == 0 && irow < N)
        P.zp[(size_t)split * rowsTot + (size_t)b * N + irow] = zacc;
}

__global__ __launch_bounds__(256)
void agg2_k(AggP V, AggP O, int GVb) {
    __shared__ SharedAggM sm;
    int bid = blockIdx.x;
    if (bid < GVb) agg_body(sm, V, bid);
    else           agg_body(sm, O, bid - GVb);
}

// ---------------- 256-thread fp32 tile FMA (cross kernels) ----------------
__device__ __forceinline__ void tile_fma256(const float (*hs)[HD], const float (*ws)[WP],
                                            int rg, int c0, float acc[4][8]) {
#pragma unroll 8
    for (int jl = 0; jl < JT; ++jl) {
        float4 h0 = *(const float4*)&hs[jl][c0];
        float4 h1 = *(const float4*)&hs[jl][c0 + 64];
        float4 w4 = *(const float4*)&ws[jl][rg * 4];
        float wq[4] = {w4.x, w4.y, w4.z, w4.w};
#pragma unroll
        for (int q = 0; q < 4; ++q) {
            float w = wq[q];
            acc[q][0] = fmaf(w, h0.x, acc[q][0]);
            acc[q][1] = fmaf(w, h0.y, acc[q][1]);
            acc[q][2] = fmaf(w, h0.z, acc[q][2]);
            acc[q][3] = fmaf(w, h0.w, acc[q][3]);
            acc[q][4] = fmaf(w, h1.x, acc[q][4]);
            acc[q][5] = fmaf(w, h1.y, acc[q][5]);
            acc[q][6] = fmaf(w, h1.z, acc[q][6]);
            acc[q][7] = fmaf(w, h1.w, acc[q][7]);
        }
    }
}

__device__ __forceinline__ void part_store256(float* __restrict__ pp, size_t base,
                                              int i0, int N, int rg, int c0,
                                              float acc[4][8]) {
#pragma unroll
    for (int q = 0; q < 4; ++q) {
        int i = i0 + rg * 4 + q;
        if (i >= N) continue;
        float* op = pp + base + (size_t)i * HD;
        *(float4*)&op[c0]      = make_float4(acc[q][0], acc[q][1], acc[q][2], acc[q][3]);
        *(float4*)&op[c0 + 64] = make_float4(acc[q][4], acc[q][5], acc[q][6], acc[q][7]);
    }
}

struct SharedTile { float hs[2][JT][HD]; float ws[2][JT][WP]; };

// ---------------- fused cross (vo + ov), pipelined fp32 ----------------
__device__ void cross_vo_body(SharedTile& sm, const CrossP& P, int lbid) {
    int tiles = P.tiles;
    int split = lbid / (8 * tiles);
    int rem = lbid - split * 8 * tiles;
    int b = rem / tiles;
    int i0 = (rem - b * tiles) * IT;
    int NVl = P.iN, NOl = P.jN;
    int j_begin = split * P.tps * JT;
    if (j_begin >= NOl) return;
    int j_end = j_begin + P.tps * JT;
    if (j_end > NOl) j_end = NOl;
    int T = (j_end - j_begin + JT - 1) / JT;
    int t = threadIdx.x;
    int rg = t >> 4, c0 = (t & 15) * 4;
    int il = t & 63, jlb = t >> 6;
    float acc[4][8];
#pragma unroll
    for (int q = 0; q < 4; ++q)
#pragma unroll
        for (int x = 0; x < 8; ++x) acc[q][x] = 0.f;
    const float* Ab = P.A + (size_t)b * NOl * NVl;
    const float* srcb = P.src + (size_t)b * NOl * HD;
    int v = i0 + il;
    float w8[8];
    stage_tile_async(srcb + (size_t)j_begin * HD, &sm.hs[0][0][0], t);
#pragma unroll
    for (int k = 0; k < 8; ++k) {
        int o = j_begin + jlb + k * 4;
        w8[k] = (v < NVl && o < NOl) ? Ab[(size_t)o * NVl + v] : 0.f;
    }
    for (int tt = 0; tt < T; ++tt) {
        int cur = tt & 1;
#pragma unroll
        for (int k = 0; k < 8; ++k) sm.ws[cur][jlb + k * 4][il] = w8[k];
        __syncthreads();
        if (tt + 1 < T) {
            int jn = j_begin + (tt + 1) * JT;
            stage_tile_async(srcb + (size_t)jn * HD, &sm.hs[1 - cur][0][0], t);
#pragma unroll
            for (int k = 0; k < 8; ++k) {
                int o = jn + jlb + k * 4;
                w8[k] = (v < NVl && o < NOl) ? Ab[(size_t)o * NVl + v] : 0.f;
            }
        }
        tile_fma256(sm.hs[cur], sm.ws[cur], rg, c0, acc);
    }
    size_t rowsTot = (size_t)8 * NVl;
    part_store256(P.pp, ((size_t)split * rowsTot + (size_t)b * NVl) * HD, i0, NVl, rg, c0, acc);
}

__device__ void cross_ov_body(SharedTile& sm, const CrossP& P, int lbid) {
    int tiles = P.tiles;
    int split = lbid / (8 * tiles);
    int rem = lbid - split * 8 * tiles;
    int b = rem / tiles;
    int i0 = (rem - b * tiles) * IT;
    int NOl = P.iN, NVl = P.jN;
    int j_begin = split * P.tps * JT;
    if (j_begin >= NVl) return;
    int j_end = j_begin + P.tps * JT;
    if (j_end > NVl) j_end = NVl;
    int T = (j_end - j_begin + JT - 1) / JT;
    int t = threadIdx.x;
    int rg = t >> 4, c0 = (t & 15) * 4;
    int il = t >> 2, j4 = (t & 3) * 4;
    float acc[4][8];
#pragma unroll
    for (int q = 0; q < 4; ++q)
#pragma unroll
        for (int x = 0; x < 8; ++x) acc[q][x] = 0.f;
    const float* Ab = P.A + (size_t)b * NOl * NVl;
    const float* srcb = P.src + (size_t)b * NVl * HD;
    const float* r1b = P.rs1 + (size_t)b * NVl;
    int orow = i0 + il;
    float4 a4[2], r4[2];
    stage_tile_async(srcb + (size_t)j_begin * HD, &sm.hs[0][0][0], t);
#pragma unroll
    for (int k = 0; k < 2; ++k) {
        int vv = j_begin + j4 + k * 16;
        float4 av = make_float4(0.f,0.f,0.f,0.f), rv = make_float4(0.f,0.f,0.f,0.f);
        if (orow < NOl) {
            if (vv + 3 < NVl) {
                av = *(const float4*)&Ab[(size_t)orow * NVl + vv];
                rv = *(const float4*)&r1b[vv];
            } else {
                float* ap = (float*)&av; float* rp = (float*)&rv;
                for (int r = 0; r < 4; ++r)
                    if (vv + r < NVl) { ap[r] = Ab[(size_t)orow * NVl + vv + r]; rp[r] = r1b[vv + r]; }
            }
        }
        a4[k] = av; r4[k] = rv;
    }
    for (int tt = 0; tt < T; ++tt) {
        int cur = tt & 1;
#pragma unroll
        for (int k = 0; k < 2; ++k) {
            float wv[4] = {a4[k].x * r4[k].x, a4[k].y * r4[k].y,
                           a4[k].z * r4[k].z, a4[k].w * r4[k].w};
#pragma unroll
            for (int r = 0; r < 4; ++r) sm.ws[cur][j4 + r + k * 16][il] = wv[r];
        }
        __syncthreads();
        if (tt + 1 < T) {
            int jn = j_begin + (tt + 1) * JT;
            stage_tile_async(srcb + (size_t)jn * HD, &sm.hs[1 - cur][0][0], t);
#pragma unroll
            for (int k = 0; k < 2; ++k) {
                int vv = jn + j4 + k * 16;
                float4 av = make_float4(0.f,0.f,0.f,0.f), rv = make_float4(0.f,0.f,0.f,0.f);
                if (orow < NOl) {
                    if (vv + 3 < NVl) {
                        av = *(const float4*)&Ab[(size_t)orow * NVl + vv];
                        rv = *(const float4*)&r1b[vv];
                    } else {
                        float* ap = (float*)&av; float* rp = (float*)&rv;
                        for (int r = 0; r < 4; ++r)
                            if (vv + r < NVl) { ap[r] = Ab[(size_t)orow * NVl + vv + r]; rp[r] = r1b[vv + r]; }
                    }
                }
                a4[k] = av; r4[k] = rv;
            }
        }
        tile_fma256(sm.hs[cur], sm.ws[cur], rg, c0, acc);
    }
    size_t rowsTot = (size_t)8 * NOl;
    part_store256(P.pp, ((size_t)split * rowsTot + (size_t)b * NOl) * HD, i0, NOl, rg, c0, acc);
}

__global__ __launch_bounds__(256)
void cross2_k(CrossP VO, CrossP OV, int GVOb) {
    __shared__ SharedTile sm;
    int bid = blockIdx.x;
    if (bid < GVOb) cross_vo_body(sm, VO, bid);
    else            cross_ov_body(sm, OV, bid - GVOb);
}

// ---------------- fused finalize GAT: sum S partials, /Z, relu ----------------
__global__ __launch_bounds__(256)
void fin2_k(FinP V, FinP O, int GVb) {
    int bid = blockIdx.x;
    const FinP& P = (bid < GVb) ? V : O;
    int idx = ((bid < GVb) ? bid : bid - GVb) * 256 + threadIdx.x;
    int rows = P.rows;
    int row = idx >> 5;
    if (row >= rows) return;
    float4 v = make_float4(0.f, 0.f, 0.f, 0.f);
    for (int s = 0; s < P.S; ++s) {
        float4 p = ((const float4*)P.pp)[((size_t)s * rows + row) * 32 + (idx & 31)];
        v.x += p.x; v.y += p.y; v.z += p.z; v.w += p.w;
    }
    float z = 0.f;
    for (int s = 0; s < P.S; ++s) z += P.zp[(size_t)s * rows + row];
    float sc = 1.f / z;
    v.x = fmaxf(v.x * sc, 0.f); v.y = fmaxf(v.y * sc, 0.f);
    v.z = fmaxf(v.z * sc, 0.f); v.w = fmaxf(v.w * sc, 0.f);
    ((float4*)P.out)[idx] = v;
}

// ---------------- fused MLP: out = (relu(x@W1+b1))@W2 + b2 + res ----------------
__global__ __launch_bounds__(128)
void mlp2_k(MlpP V, MlpP O, int GVb) {
    __shared__ float xs[8][HD];
    __shared__ float hh[8][HD];
    int bid = blockIdx.x;
    const MlpP& P = (bid < GVb) ? V : O;
    int row0 = ((bid < GVb) ? bid : bid - GVb) * 8;
    int rows = P.rows;
    int t = threadIdx.x;
    for (int l = t; l < 8 * 32; l += 128) {
        int r = l >> 5, c4 = l & 31;
        int row = row0 + r;
        float4 v = make_float4(0.f, 0.f, 0.f, 0.f);
        if (row < rows) {
            for (int s = 0; s < P.S; ++s) {
                float4 p = ((const float4*)P.pp)[((size_t)s * rows + row) * 32 + c4];
                v.x += p.x; v.y += p.y; v.z += p.z; v.w += p.w;
            }
            float sc = P.scale[row];
            v.x *= sc; v.y *= sc; v.z *= sc; v.w *= sc;
        }
        ((float4*)&xs[r][0])[c4] = v;
    }
    __syncthreads();
    int wv = t >> 6, tt = t & 63, rb = wv * 4;
    float a0[4] = {0.f, 0.f, 0.f, 0.f}, a1v[4] = {0.f, 0.f, 0.f, 0.f};
#pragma unroll 4
    for (int k = 0; k < HD; ++k) {
        float w0 = P.W1[(size_t)k * HD + tt];
        float w1 = P.W1[(size_t)k * HD + tt + 64];
#pragma unroll
        for (int r = 0; r < 4; ++r) {
            float x = xs[rb + r][k];
            a0[r] = fmaf(x, w0, a0[r]);
            a1v[r] = fmaf(x, w1, a1v[r]);
        }
    }
    float bb0 = P.b1[tt], bb1 = P.b1[tt + 64];
#pragma unroll
    for (int r = 0; r < 4; ++r) {
        hh[rb + r][tt]      = fmaxf(a0[r] + bb0, 0.f);
        hh[rb + r][tt + 64] = fmaxf(a1v[r] + bb1, 0.f);
    }
    __syncthreads();
    float c0a[4] = {0.f, 0.f, 0.f, 0.f}, c1a[4] = {0.f, 0.f, 0.f, 0.f};
#pragma unroll 4
    for (int k = 0; k < HD; ++k) {
        float w0 = P.W2[(size_t)k * HD + tt];
        float w1 = P.W2[(size_t)k * HD + tt + 64];
#pragma unroll
        for (int r = 0; r < 4; ++r) {
            float x = hh[rb + r][k];
            c0a[r] = fmaf(x, w0, c0a[r]);
            c1a[r] = fmaf(x, w1, c1a[r]);
        }
    }
    float d0 = P.b2[tt], d1 = P.b2[tt + 64];
#pragma unroll
    for (int r = 0; r < 4; ++r) {
        int row = row0 + rb + r;
        if (row >= rows) continue;
        P.out[(size_t)row * HD + tt]      = c0a[r] + d0 + P.res[(size_t)row * HD + tt];
        P.out[(size_t)row * HD + tt + 64] = c1a[r] + d1 + P.res[(size_t)row * HD + tt + 64];
    }
}

// ---------------- output projection ----------------
template<int RELU, int BIAS, int RES>
__global__ __launch_bounds__(128)
void linear_k(const float* __restrict__ X, const float* __restrict__ W,
              const float* __restrict__ bias, const float* __restrict__ res,
              float* __restrict__ out, int rows, int K, int Dout) {
    __shared__ float xs[4][512];
    int row0 = blockIdx.x * 4;
    int t = threadIdx.x;
    int K4 = K >> 2;
    for (int l = t; l < 4 * K4; l += 128) {
        int r = l / K4, c4 = l - r * K4;
        float4 val = make_float4(0.f, 0.f, 0.f, 0.f);
        if (row0 + r < rows) val = ((const float4*)(X + (size_t)(row0 + r) * K))[c4];
        ((float4*)&xs[r][0])[c4] = val;
    }
    __syncthreads();
    int chunk = Dout < 256 ? Dout : 256;
    int half = chunk >> 1;
    if (t >= half) return;
    int c0 = blockIdx.y * chunk + t;
    int c1 = c0 + half;
    float a00 = 0, a01 = 0, a02 = 0, a03 = 0, a10 = 0, a11 = 0, a12 = 0, a13 = 0;
#pragma unroll 4
    for (int k = 0; k < K; ++k) {
        float w0 = W[(size_t)k * Dout + c0];
        float w1 = W[(size_t)k * Dout + c1];
        float x0 = xs[0][k], x1 = xs[1][k], x2 = xs[2][k], x3 = xs[3][k];
        a00 = fmaf(x0, w0, a00); a01 = fmaf(x1, w0, a01);
        a02 = fmaf(x2, w0, a02); a03 = fmaf(x3, w0, a03);
        a10 = fmaf(x0, w1, a10); a11 = fmaf(x1, w1, a11);
        a12 = fmaf(x2, w1, a12); a13 = fmaf(x3, w1, a13);
    }
    float accs[2][4] = {{a00, a01, a02, a03}, {a10, a11, a12, a13}};
    int cs[2] = {c0, c1};
    for (int h = 0; h < 2; ++h) {
        float bv = BIAS ? bias[cs[h]] : 0.f;
        for (int r = 0; r < 4; ++r) {
            int row = row0 + r;
            if (row >= rows) continue;
            float v = accs[h][r] + bv;
            if (RES) v += res[(size_t)row * Dout + cs[h]];
            if (RELU) v = fmaxf(v, 0.f);
            out[(size_t)row * Dout + cs[h]] = v;
        }
    }
}

// ---------------- host launcher ----------------
extern "C" void kernel_launch(void* const* d_in, const int* in_sizes, int n_in,
                              void* d_out, int out_size, void* d_ws, size_t ws_size,
                              hipStream_t stream) {
    const int B = 8, NV = 500, NO = 1500, DV = 512, DO = 32;
    const float* vis_memory = (const float*)d_in[0];
    const float* obj_memory = (const float*)d_in[1];
    const float* vis_adj    = (const float*)d_in[2];
    const float* obj_adj    = (const float*)d_in[3];
    const float* A_OV       = (const float*)d_in[4];
    const float* Wv1  = (const float*)d_in[5];
    const float* av1a = (const float*)d_in[6];
    const float* av1b = (const float*)d_in[7];
    const float* Wv2  = (const float*)d_in[8];
    const float* av2a = (const float*)d_in[9];
    const float* av2b = (const float*)d_in[10];
    const float* Wo1  = (const float*)d_in[11];
    const float* ao1a = (const float*)d_in[12];
    const float* ao1b = (const float*)d_in[13];
    const float* Wo2  = (const float*)d_in[14];
    const float* ao2a = (const float*)d_in[15];
    const float* ao2b = (const float*)d_in[16];
    const float* g2o_W1 = (const float*)d_in[17];
    const float* g2o_b1 = (const float*)d_in[18];
    const float* g2o_W2 = (const float*)d_in[19];
    const float* g2o_b2 = (const float*)d_in[20];
    const float* o2g_W1 = (const float*)d_in[21];
    const float* o2g_b1 = (const float*)d_in[22];
    const float* o2g_W2 = (const float*)d_in[23];
    const float* o2g_b2 = (const float*)d_in[24];
    const float* img_W = (const float*)d_in[25];
    const float* img_b = (const float*)d_in[26];
    const float* obj_W = (const float*)d_in[27];
    const float* obj_b = (const float*)d_in[28];

    const int tilesJV = 16, tilesJO = 47;            // ceil(N/32)

    float* wsp = (float*)d_ws;
    size_t off = 0;
    auto alloc = [&](size_t n) { float* p = wsp + off; off += n; return p; };
    float* rs1   = alloc(B * NV);
    float* rs2   = alloc(B * NO);
    float* saV   = alloc(B * NV);
    float* sbV   = alloc(B * NV);
    float* smV   = alloc(B);
    float* saO   = alloc(B * NO);
    float* sbO   = alloc(B * NO);
    float* smO   = alloc(B);
    float* s1p   = alloc((size_t)B * CCH * NV);
    unsigned short* hTv = (unsigned short*)alloc((size_t)B * tilesJV * 4096 / 2);
    unsigned short* hTo = (unsigned short*)alloc((size_t)B * tilesJO * 4096 / 2);
    float* v1    = alloc((size_t)B * NV * HD);
    float* o1    = alloc((size_t)B * NO * HD);
    float* visb  = alloc((size_t)B * NV * HD);
    float* objb  = alloc((size_t)B * NO * HD);
    float* ppV   = alloc((size_t)8 * B * NV * HD);
    float* zpV   = alloc((size_t)8 * B * NV);
    float* ppO   = alloc((size_t)4 * B * NO * HD);
    float* zpO   = alloc((size_t)4 * B * NO);
    alloc(16384);                                    // tail pad for async OOB reads

    colsum_part_k<<<dim3((NV + 255) / 256, CCH, B), 256, 0, stream>>>(A_OV, s1p, B, NO, NV);
    colsum_fin_k<<<dim3((B * NV + 255) / 256), 256, 0, stream>>>(s1p, rs1, B, NV);
    rowsum_inv_k<<<dim3((B * NO + 3) / 4), 256, 0, stream>>>(A_OV, rs1, rs2, B, NO, NV);

    // geometry (IT=64, JT=32):
    const int tilesV = 8, tilesO = 24;               // ceil(N/64)
    const int SV = 8, SO = 4, SVO = 8, SOV = 4;
    const int tpsV = 2;    // ceil(16/8)  j-tiles per split (vis GAT)
    const int tpsO = 12;   // ceil(47/4)  j-tiles per split (obj GAT)
    const int tpsVO = 6;   // ceil(ceil(1500/32)/8)
    const int tpsOV = 4;   // ceil(ceil(500/32)/4)
    const int G_AGG_V = B * tilesV * SV;             // 512
    const int G_AGG_O = B * tilesO * SO;             // 768
    const int G_CR_VO = B * tilesV * SVO;            // 512
    const int G_CR_OV = B * tilesO * SOV;            // 768
    const int G_GATH_V = B * NV / 8;                 // 500
    const int G_GATH_O = B * NO / 8;                 // 1500
    const int G_FIN_V = B * NV * 32 / 256;           // 500
    const int G_FIN_O = B * NO * 32 / 256;           // 1500

    auto layer = [&](const float* Xv, int Kv, const float* Wv_, const float* a1v_, const float* a2v_,
                     const float* Xo, int Ko, const float* Wo_, const float* a1o_, const float* a2o_,
                     float* visout, float* objout) {
        GathP gv{Xv, Wv_, a1v_, a2v_, hTv, saV, sbV, B * NV, Kv, NV, tilesJV};
        GathP go{Xo, Wo_, a1o_, a2o_, hTo, saO, sbO, B * NO, Ko, NO, tilesJO};
        int maxK = Kv > Ko ? Kv : Ko;
        gath2_k<<<G_GATH_V + G_GATH_O, 128, 8 * maxK * 4, stream>>>(gv, go, G_GATH_V);
        sbmax2_k<<<16, 256, 0, stream>>>(sbV, smV, sbO, smO, NV, NO);
        AggP av{vis_adj, saV, sbV, smV, hTv, ppV, zpV, NV, tilesV, tilesJV, tpsV};
        AggP ao{obj_adj, saO, sbO, smO, hTo, ppO, zpO, NO, tilesO, tilesJO, tpsO};
        agg2_k<<<G_AGG_V + G_AGG_O, THR, 0, stream>>>(av, ao, G_AGG_V);
        FinP fv{ppV, zpV, v1, B * NV, SV};
        FinP fo{ppO, zpO, o1, B * NO, SO};
        fin2_k<<<G_FIN_V + G_FIN_O, 256, 0, stream>>>(fv, fo, G_FIN_V);
        CrossP cvo{A_OV, o1, nullptr, ppV, NV, NO, tilesV, tpsVO};
        CrossP cov{A_OV, v1, rs1, ppO, NO, NV, tilesO, tpsOV};
        cross2_k<<<G_CR_VO + G_CR_OV, THR, 0, stream>>>(cvo, cov, G_CR_VO);
        MlpP mv{ppV, rs1, SVO, o2g_W1, o2g_b1, o2g_W2, o2g_b2, v1, visout, B * NV};
        MlpP mo{ppO, rs2, SOV, g2o_W1, g2o_b1, g2o_W2, g2o_b2, o1, objout, B * NO};
        mlp2_k<<<G_GATH_V + G_GATH_O, 128, 0, stream>>>(mv, mo, G_GATH_V);
    };

    // layer 1
    layer(vis_memory, DV, Wv1, av1a, av1b, obj_memory, DO, Wo1, ao1a, ao1b, visb, objb);
    // layer 2
    layer(visb, HD, Wv2, av2a, av2b, objb, HD, Wo2, ao2a, ao2b, visb, objb);

    // output projections
    float* vis_out = (float*)d_out;
    float* obj_out = vis_out + (size_t)B * NV * DV;
    linear_k<0, 1, 0><<<dim3((B * NV + 3) / 4, (DV + 255) / 256), 128, 0, stream>>>(
        visb, img_W, img_b, nullptr, vis_out, B * NV, HD, DV);
    linear_k<0, 1, 0><<<dim3((B * NO + 3) / 4, 1), 128, 0, stream>>>(
        objb, obj_W, obj_b, nullptr, obj_out, B * NO, HD, DO);
}